// Round 8
// baseline (498.370 us; speedup 1.0000x reference)
//
#include <hip/hip_runtime.h>

#define BB 16
#define NN 1024
#define KNN 20
#define BNEPS 1e-5f

typedef __attribute__((ext_vector_type(8))) short short8;
typedef __attribute__((ext_vector_type(4))) float f32x4;

__device__ __forceinline__ float4 ld4(const float* p){ return *(const float4*)p; }
__device__ __forceinline__ void fma4(float4& a, float s, float4 w){
  a.x = fmaf(s, w.x, a.x); a.y = fmaf(s, w.y, a.y);
  a.z = fmaf(s, w.z, a.z); a.w = fmaf(s, w.w, a.w);
}
__device__ __forceinline__ void max4(float4& a, float4 v){
  a.x = fmaxf(a.x, v.x); a.y = fmaxf(a.y, v.y);
  a.z = fmaxf(a.z, v.z); a.w = fmaxf(a.w, v.w);
}
__device__ __forceinline__ unsigned short f2bf(float f){
  unsigned int u = __float_as_uint(f);
  u = (u + 0x7FFF + ((u >> 16) & 1)) >> 16;   // RNE, finite inputs
  return (unsigned short)u;
}
__device__ __forceinline__ float bf2f(unsigned short u){
  return __uint_as_float(((unsigned int)u) << 16);
}
__device__ __forceinline__ f32x4 mfma16(short8 a, short8 b, f32x4 c){
  return __builtin_amdgcn_mfma_f32_16x16x32_bf16(a, b, c, 0, 0, 0);
}

// build exact (value desc, index asc) top-3 of a lane's 16 row elements, excluding km bits
__device__ __forceinline__ void top3_build(const float* rp, int kmr,
                                           float& a0, float& a1, float& a2,
                                           int& i0, int& i1, int& i2){
  a0 = -1e30f; a1 = -1e30f; a2 = -1e30f; i0 = 0; i1 = 0; i2 = 0;
#pragma unroll
  for (int r = 0; r < 4; r++){
    float4 t = ld4(rp + r*4);
    float tv[4] = {t.x, t.y, t.z, t.w};
#pragma unroll
    for (int q = 0; q < 4; q++){
      int e = r*4 + q;
      float v = ((kmr >> e) & 1) ? -1e30f : tv[q];
      bool b0 = v > a0, b1 = v > a1, b2 = v > a2;
      a2 = b1 ? a1 : (b2 ? v : a2); i2 = b1 ? i1 : (b2 ? e : i2);
      a1 = b0 ? a0 : (b1 ? v : a1); i1 = b0 ? i0 : (b1 ? e : i1);
      a0 = b0 ? v  : a0;            i0 = b0 ? e : i0;
    }
  }
}

// ---- transpose x (B,3,N) -> xt (B,N,4) fp32 (for uv1); packed split-bf16 MFMA operands
//      embedded in hlo's unused channel space (per-row: A at +256, B at +288, 32 shorts each)
//      A = [hi|lo|hi|0..] (K=32), B = [hi|hi|lo|0..]; sq from hi+lo for consistency ----
__global__ __launch_bounds__(256) void k_transpose(const float* __restrict__ x, float* __restrict__ xt,
                                                   unsigned short* __restrict__ hlo,
                                                   float* __restrict__ sq){
  int i = blockIdx.x*256 + threadIdx.x;
  if (i >= BB*NN) return;
  int b = i >> 10, n = i & 1023;
  const float* xb = x + (size_t)b*3*NN;
  float4 v;
  v.x = xb[0*NN+n]; v.y = xb[1*NN+n]; v.z = xb[2*NN+n]; v.w = 0.f;
  ((float4*)xt)[i] = v;
  unsigned short hx = f2bf(v.x), hy = f2bf(v.y), hz = f2bf(v.z);
  float rx = v.x - bf2f(hx), ry = v.y - bf2f(hy), rz = v.z - bf2f(hz);
  unsigned short lx = f2bf(rx), ly = f2bf(ry), lz = f2bf(rz);
  float ex = bf2f(hx)+bf2f(lx), ey = bf2f(hy)+bf2f(ly), ez = bf2f(hz)+bf2f(lz);
  sq[i] = ex*ex + ey*ey + ez*ez;          // consistent with Gram inputs
  ushort4 h4 = {hx, hy, hz, 0};
  ushort4 l4 = {lx, ly, lz, 0};
  ushort4 z4 = {0, 0, 0, 0};
  unsigned short* pa = hlo + (size_t)i*512 + 256;
  unsigned short* pb = hlo + (size_t)i*512 + 288;
  *(ushort4*)(pa+0) = h4; *(ushort4*)(pa+4) = l4; *(ushort4*)(pa+8) = h4;
  *(ushort4*)(pb+0) = h4; *(ushort4*)(pb+4) = h4; *(ushort4*)(pb+8) = l4;
#pragma unroll
  for (int s = 12; s < 32; s += 4){ *(ushort4*)(pa+s) = z4; *(ushort4*)(pb+s) = z4; }
}

// ---- device preps ----
__device__ __forceinline__ void prep_w_dev(int i, const float* w, const float* bnp,
                                           float* wlT, float* dT, float* bias, int Cin, int Cpad, int Cout){
  if (i >= Cpad*Cout) return;
  int c = i / Cout, o = i - c*Cout;
  float s = bnp[o] * rsqrtf(bnp[3*Cout+o] + BNEPS);
  float wl = (c < Cin) ? w[(size_t)o*2*Cin + c] : 0.f;
  float wr = (c < Cin) ? w[(size_t)o*2*Cin + Cin + c] : 0.f;
  wlT[i] = wl * s;
  dT[i]  = (wr - wl) * s;
  if (c == 0) bias[o] = bnp[Cout+o] - bnp[2*Cout+o]*s;
}
__device__ __forceinline__ void prep_wbf_dev(int i, const float* w, const float* bnp,
                                             unsigned short* wlB, unsigned short* dB, float* bias,
                                             int Cin, int Cout){
  if (i >= Cin*Cout) return;
  int o = i / Cin, c = i - o*Cin;
  float s = bnp[o] * rsqrtf(bnp[3*Cout+o] + BNEPS);
  float wl = w[(size_t)o*2*Cin + c] * s;
  float wr = w[(size_t)o*2*Cin + Cin + c] * s;
  wlB[i] = f2bf(wl);
  dB[i]  = f2bf(wr - wl);
  if (c == 0) bias[o] = bnp[Cout+o] - bnp[2*Cout+o]*s;
}

// ---- single merged prep kernel ----
__global__ __launch_bounds__(256) void k_prep_all(const float* __restrict__ w1, const float* __restrict__ bn1,
                                                  const float* __restrict__ w2, const float* __restrict__ bn2,
                                                  const float* __restrict__ w3, const float* __restrict__ bn3,
                                                  const float* __restrict__ w4, const float* __restrict__ bn4,
                                                  const float* __restrict__ w5, const float* __restrict__ bn5,
                                                  float* __restrict__ wlT1, float* __restrict__ dT1, float* __restrict__ bias1,
                                                  unsigned short* __restrict__ wlB2, unsigned short* __restrict__ dB2, float* __restrict__ bias2,
                                                  unsigned short* __restrict__ wlB3, unsigned short* __restrict__ dB3, float* __restrict__ bias3,
                                                  unsigned short* __restrict__ wlB4, unsigned short* __restrict__ dB4, float* __restrict__ bias4,
                                                  unsigned short* __restrict__ w5b, float* __restrict__ b5){
  int bid = blockIdx.x, t = threadIdx.x;
  if (bid < 1){
    prep_w_dev(t, w1, bn1, wlT1, dT1, bias1, 3, 4, 64);
  } else if (bid < 17){
    prep_wbf_dev((bid-1)*256 + t, w2, bn2, wlB2, dB2, bias2, 64, 64);
  } else if (bid < 49){
    prep_wbf_dev((bid-17)*256 + t, w3, bn3, wlB3, dB3, bias3, 64, 128);
  } else if (bid < 177){
    prep_wbf_dev((bid-49)*256 + t, w4, bn4, wlB4, dB4, bias4, 128, 256);
  } else {
    int i = (bid-177)*256 + t;
    int o = i >> 9, c = i & 511;
    float s = bn5[o] * rsqrtf(bn5[3*1024+o] + BNEPS);
    w5b[i] = f2bf(w5[(size_t)o*512 + c] * s);
    if (c == 0) b5[o] = bn5[1024+o] - bn5[2*1024+o]*s;
  }
}

// ---------------- sq[row] = |hi+lo|^2 from bf16 hi/lo activations (L2-L4) ----------------
template<int CC>
__global__ __launch_bounds__(256) void k_sqb(const unsigned short* __restrict__ hb,
                                             const unsigned short* __restrict__ hlo,
                                             float* __restrict__ sq){
  int i = blockIdx.x*256 + threadIdx.x;
  if (i >= BB*NN) return;
  const unsigned short* ph = hb  + (size_t)i*512;
  const unsigned short* pl = hlo + (size_t)i*512;
  float s = 0.f;
#pragma unroll
  for (int c = 0; c < CC; c += 4){
    ushort4 a = *(const ushort4*)(ph + c);
    ushort4 b = *(const ushort4*)(pl + c);
    float v0 = bf2f(a.x)+bf2f(b.x), v1 = bf2f(a.y)+bf2f(b.y);
    float v2 = bf2f(a.z)+bf2f(b.z), v3 = bf2f(a.w)+bf2f(b.w);
    s += v0*v0 + v1*v1 + v2*v2 + v3*v3;
  }
  sq[i] = s;
}

// ======== FUSED pd + top-k: one block = 16-row stripe x 1024 cols, pd lives in LDS ========
// Compute: split-bf16 MFMA Gram (hi*hi + lo*hi + hi*lo), A-frag (16 rows) in registers,
// B-frags streamed from global (L2-resident: 1024-block grid XCD-pinned per batch).
// Select: verbatim k_topk logic on LDS rows (stride 1028 floats: 16B-aligned rows,
// 2-way bank alias on reads = free; write phase 2-way = free).
// pd NEVER touches HBM: eliminates 64MB write + 64MB read per layer.
#define PDSTR 1028
template<int CC>
__global__ __launch_bounds__(256) void k_pdtopk(const unsigned short* __restrict__ hbi,
                                                const unsigned short* __restrict__ hloi,
                                                const float* __restrict__ sq,
                                                int* __restrict__ idxOut){
  __shared__ float pdrow[16*PDSTR];
  const int tid = threadIdx.x, lane = tid & 63, w = tid >> 6;
  const int l15 = lane & 15, quad = lane >> 4;
  const int bid = blockIdx.x;
  const int xcd = bid & 7, j = bid >> 3;
  const int b = xcd + ((j >> 6) << 3);     // batches {xcd, xcd+8} pinned to one XCD
  const int stripe = j & 63;
  const size_t ar0 = (size_t)b*NN + stripe*16;
  const size_t brow = (size_t)b*NN;

  constexpr int KF = CC/32;
  // A fragments: 16 rows x 3 segments x KF k-steps, in registers
  short8 afr[3*KF];
#pragma unroll
  for (int s = 0; s < 3; s++){
    const unsigned short* Ap = (s == 1) ? hloi : hbi;   // hi, lo, hi
#pragma unroll
    for (int k = 0; k < KF; k++)
      afr[s*KF + k] = *(const short8*)(Ap + (ar0 + l15)*512 + k*32 + quad*8);
  }

  f32x4 zero = {0.f,0.f,0.f,0.f};
#pragma unroll
  for (int c = 0; c < 16; c++){
    const int colb = (w*16 + c)*16;
    f32x4 acc = zero;
#pragma unroll
    for (int s = 0; s < 3; s++){
      const unsigned short* Bp = (s == 2) ? hloi : hbi; // hi, hi, lo
#pragma unroll
      for (int k = 0; k < KF; k++){
        short8 bf = *(const short8*)(Bp + (brow + colb + l15)*512 + k*32 + quad*8);
        acc = mfma16(afr[s*KF + k], bf, acc);
      }
    }
    float sqv = sq[b*NN + colb + l15];
#pragma unroll
    for (int r = 0; r < 4; r++)
      pdrow[(quad*4 + r)*PDSTR + colb + l15] = 2.f*acc[r] - sqv;
  }
  __syncthreads();

  // ---- top-k (k=20) on the 16 LDS rows: 4 waves x 2 rows x 2 passes ----
  for (int p = 0; p < 2; p++){
    const int rl0 = p*8 + w*2;
    const float* row0 = pdrow + rl0*PDSTR + lane*16;
    const float* row1 = row0 + PDSTR;

    float c0v[2], c1v[2], c2v[2];
    int   c0i[2], c1i[2], c2i[2];
    int   km[2] = {0, 0};
    top3_build(row0, 0, c0v[0], c1v[0], c2v[0], c0i[0], c1i[0], c2i[0]);
    top3_build(row1, 0, c0v[1], c1v[1], c2v[1], c0i[1], c1i[1], c2i[1]);

    int* out0 = idxOut + (ar0 + rl0)*KNN;
    int* out1 = out0 + KNN;
    for (int it = 0; it < KNN; it++){
      float g0 = c0v[0], g1 = c0v[1];
#pragma unroll
      for (int s = 1; s < 64; s <<= 1){
        g0 = fmaxf(g0, __shfl_xor(g0, s));
        g1 = fmaxf(g1, __shfl_xor(g1, s));
      }
      int o0 = __ffsll(__ballot(c0v[0] == g0)) - 1;
      int o1 = __ffsll(__ballot(c0v[1] == g1)) - 1;
      bool u0 = (lane == o0), u1 = (lane == o1);
      if (u0) out0[it] = lane*16 + c0i[0];
      if (u1) out1[it] = lane*16 + c0i[1];
      km[0] |= u0 ? (1 << c0i[0]) : 0;
      km[1] |= u1 ? (1 << c0i[1]) : 0;
      c0v[0] = u0 ? c1v[0] : c0v[0];  c0i[0] = u0 ? c1i[0] : c0i[0];
      c1v[0] = u0 ? c2v[0] : c1v[0];  c1i[0] = u0 ? c2i[0] : c1i[0];
      c2v[0] = u0 ? -1e30f : c2v[0];
      c0v[1] = u1 ? c1v[1] : c0v[1];  c0i[1] = u1 ? c1i[1] : c0i[1];
      c1v[1] = u1 ? c2v[1] : c1v[1];  c1i[1] = u1 ? c2i[1] : c1i[1];
      c2v[1] = u1 ? -1e30f : c2v[1];
      if (it < KNN-1){
        bool rp0 = (c0v[0] == -1e30f) && (km[0] != 0xFFFF);
        bool rp1 = (c0v[1] == -1e30f) && (km[1] != 0xFFFF);
        if (__ballot(rp0 || rp1)){
          if (rp0) top3_build(row0, km[0], c0v[0], c1v[0], c2v[0], c0i[0], c1i[0], c2i[0]);
          if (rp1) top3_build(row1, km[1], c0v[1], c1v[1], c2v[1], c0i[1], c1i[1], c2i[1]);
        }
      }
    }
  }
}

// -------- L1 fused pd+topk: packed K=32 operands in hlo (row*512+256 / +288) --------
__global__ __launch_bounds__(256) void k_pdtopk1(const unsigned short* __restrict__ hloi,
                                                 const float* __restrict__ sq,
                                                 int* __restrict__ idxOut){
  __shared__ float pdrow[16*PDSTR];
  const int tid = threadIdx.x, lane = tid & 63, w = tid >> 6;
  const int l15 = lane & 15, quad = lane >> 4;
  const int bid = blockIdx.x;
  const int xcd = bid & 7, j = bid >> 3;
  const int b = xcd + ((j >> 6) << 3);
  const int stripe = j & 63;
  const size_t ar0 = (size_t)b*NN + stripe*16;
  const size_t brow = (size_t)b*NN;

  short8 af = *(const short8*)(hloi + (ar0 + l15)*512 + 256 + quad*8);

  f32x4 zero = {0.f,0.f,0.f,0.f};
#pragma unroll
  for (int c = 0; c < 16; c++){
    const int colb = (w*16 + c)*16;
    short8 bf = *(const short8*)(hloi + (brow + colb + l15)*512 + 288 + quad*8);
    f32x4 acc = mfma16(af, bf, zero);
    float sqv = sq[b*NN + colb + l15];
#pragma unroll
    for (int r = 0; r < 4; r++)
      pdrow[(quad*4 + r)*PDSTR + colb + l15] = 2.f*acc[r] - sqv;
  }
  __syncthreads();

  for (int p = 0; p < 2; p++){
    const int rl0 = p*8 + w*2;
    const float* row0 = pdrow + rl0*PDSTR + lane*16;
    const float* row1 = row0 + PDSTR;

    float c0v[2], c1v[2], c2v[2];
    int   c0i[2], c1i[2], c2i[2];
    int   km[2] = {0, 0};
    top3_build(row0, 0, c0v[0], c1v[0], c2v[0], c0i[0], c1i[0], c2i[0]);
    top3_build(row1, 0, c0v[1], c1v[1], c2v[1], c0i[1], c1i[1], c2i[1]);

    int* out0 = idxOut + (ar0 + rl0)*KNN;
    int* out1 = out0 + KNN;
    for (int it = 0; it < KNN; it++){
      float g0 = c0v[0], g1 = c0v[1];
#pragma unroll
      for (int s = 1; s < 64; s <<= 1){
        g0 = fmaxf(g0, __shfl_xor(g0, s));
        g1 = fmaxf(g1, __shfl_xor(g1, s));
      }
      int o0 = __ffsll(__ballot(c0v[0] == g0)) - 1;
      int o1 = __ffsll(__ballot(c0v[1] == g1)) - 1;
      bool u0 = (lane == o0), u1 = (lane == o1);
      if (u0) out0[it] = lane*16 + c0i[0];
      if (u1) out1[it] = lane*16 + c0i[1];
      km[0] |= u0 ? (1 << c0i[0]) : 0;
      km[1] |= u1 ? (1 << c0i[1]) : 0;
      c0v[0] = u0 ? c1v[0] : c0v[0];  c0i[0] = u0 ? c1i[0] : c0i[0];
      c1v[0] = u0 ? c2v[0] : c1v[0];  c1i[0] = u0 ? c2i[0] : c1i[0];
      c2v[0] = u0 ? -1e30f : c2v[0];
      c0v[1] = u1 ? c1v[1] : c0v[1];  c0i[1] = u1 ? c1i[1] : c0i[1];
      c1v[1] = u1 ? c2v[1] : c1v[1];  c1i[1] = u1 ? c2i[1] : c1i[1];
      c2v[1] = u1 ? -1e30f : c2v[1];
      if (it < KNN-1){
        bool rp0 = (c0v[0] == -1e30f) && (km[0] != 0xFFFF);
        bool rp1 = (c0v[1] == -1e30f) && (km[1] != 0xFFFF);
        if (__ballot(rp0 || rp1)){
          if (rp0) top3_build(row0, km[0], c0v[0], c1v[0], c2v[0], c0i[0], c1i[0], c2i[0]);
          if (rp1) top3_build(row1, km[1], c0v[1], c1v[1], c2v[1], c0i[1], c1i[1], c2i[1]);
        }
      }
    }
  }
}

// ---------------- L1 U|V: Z[n][0..63]=xt_n*wlT1, Z[n][64..127]=xt_n*dT1 (fp32, K=4) --------
__global__ __launch_bounds__(256) void k_uv1(const float* __restrict__ xt,
                                             const float* __restrict__ wlT, const float* __restrict__ dT,
                                             float* __restrict__ Z){
  int t = blockIdx.x*256 + threadIdx.x;
  int n = t >> 5, q = t & 31;
  float4 xv = ld4(xt + (size_t)n*4);
  const float* wp = (q < 16) ? (wlT + q*4) : (dT + (q-16)*4);
  float4 a = make_float4(0.f,0.f,0.f,0.f);
  fma4(a, xv.x, ld4(wp + 0*64));
  fma4(a, xv.y, ld4(wp + 1*64));
  fma4(a, xv.z, ld4(wp + 2*64));
  fma4(a, xv.w, ld4(wp + 3*64));
  *(float4*)(Z + (size_t)n*128 + q*4) = a;
}

// ---------------- U|V dense GEMM (bf16 MFMA) ----------------
// grid: x = data-row tile (XCD locality for the A panel), y = output-col tile
template<int K>
__global__ __launch_bounds__(256) void k_uv(const unsigned short* __restrict__ hbi,
                                            const unsigned short* __restrict__ wB,
                                            float* __restrict__ Z, int ldz){
  __shared__ char sm[20480];
  char* As = sm; char* Bs = sm + 10240;
  const int tid = threadIdx.x, lane = tid & 63, w = tid >> 6;
  const int l15 = lane & 15, quad = lane >> 4;
  const int n0 = blockIdx.y*128, r0 = blockIdx.x*128;

  f32x4 acc[2][8];
  f32x4 zero = {0.f,0.f,0.f,0.f};
#pragma unroll
  for (int i = 0; i < 2; i++)
#pragma unroll
    for (int j = 0; j < 8; j++) acc[i][j] = zero;

  for (int k0 = 0; k0 < K; k0 += 32){
#pragma unroll
    for (int i = 0; i < 2; i++){
      int e = tid + i*256;
      int r = e >> 2, sg = e & 3;
      *(float4*)(As + r*80 + sg*16) = *(const float4*)(hbi + ((size_t)(r0+r))*512 + k0 + sg*8);
      *(float4*)(Bs + r*80 + sg*16) = *(const float4*)(wB  + ((size_t)(n0+r))*K   + k0 + sg*8);
    }
    __syncthreads();
    short8 af0 = *(short8*)(As + (w*32 + l15)*80 + quad*16);
    short8 af1 = *(short8*)(As + (w*32 + 16 + l15)*80 + quad*16);
#pragma unroll
    for (int ns = 0; ns < 8; ns++){
      short8 bf = *(short8*)(Bs + (ns*16 + l15)*80 + quad*16);
      acc[0][ns] = mfma16(af0, bf, acc[0][ns]);
      acc[1][ns] = mfma16(af1, bf, acc[1][ns]);
    }
    __syncthreads();
  }

#pragma unroll
  for (int ms = 0; ms < 2; ms++){
#pragma unroll
    for (int ns = 0; ns < 8; ns++){
      f32x4 a = acc[ms][ns];
      int row = r0 + w*32 + ms*16 + quad*4;
      int col = n0 + ns*16 + l15;
#pragma unroll
      for (int r = 0; r < 4; r++)
        Z[(size_t)(row+r)*ldz + col] = a[r];
    }
  }
}

// ---------------- gather-max: emits bf16 hi (hb) and bf16 lo (hlo) ----------------
template<int COUT, int P, bool WLO>
__global__ __launch_bounds__(256) void k_gmax(const float* __restrict__ Z,
                                              const float* __restrict__ bias,
                                              const int* __restrict__ knn_idx,
                                              unsigned short* __restrict__ hbo,
                                              unsigned short* __restrict__ hloo){
  constexpr int QPP = COUT/4;
  __shared__ int idxS[P*KNN];
  const int tid = threadIdx.x;
  const int p0 = blockIdx.x * P;
  for (int t = tid; t < P*KNN; t += 256) idxS[t] = knn_idx[(size_t)p0*KNN + t];
  __syncthreads();

  const int p = tid / QPP, q = tid - p*QPP;
  const int base = p0 & ~1023;
  const int ldz = 2*COUT;
  const float* Zq = Z + q*4;

  float4 m = make_float4(-1e30f,-1e30f,-1e30f,-1e30f);
#pragma unroll
  for (int j = 0; j < KNN; j++){
    int mr = idxS[p*KNN + j];
    max4(m, ld4(Zq + (size_t)(base + mr)*ldz));
  }
  float4 ctr = ld4(Z + (size_t)(p0+p)*ldz + COUT + q*4);
  float4 bs  = ld4(bias + q*4);
  float4 y;
  y.x = m.x + ctr.x + bs.x; y.x = fmaxf(y.x, 0.2f*y.x);
  y.y = m.y + ctr.y + bs.y; y.y = fmaxf(y.y, 0.2f*y.y);
  y.z = m.z + ctr.z + bs.z; y.z = fmaxf(y.z, 0.2f*y.z);
  y.w = m.w + ctr.w + bs.w; y.w = fmaxf(y.w, 0.2f*y.w);

  size_t pi = (size_t)(p0 + p);
  ushort4 hv; hv.x = f2bf(y.x); hv.y = f2bf(y.y); hv.z = f2bf(y.z); hv.w = f2bf(y.w);
  *(ushort4*)(hbo + pi*512 + q*4) = hv;
  if (WLO){
    ushort4 lv;
    lv.x = f2bf(y.x - bf2f(hv.x)); lv.y = f2bf(y.y - bf2f(hv.y));
    lv.z = f2bf(y.z - bf2f(hv.z)); lv.w = f2bf(y.w - bf2f(hv.w));
    *(ushort4*)(hloo + pi*512 + q*4) = lv;
  }
}

// ---------------- conv5 (bf16 MFMA) + bias + lrelu + partial pool ----------------
// grid: x = data-row tile (XCD locality for hb panel), y = output-channel tile
__global__ __launch_bounds__(256) void k_conv5m(const unsigned short* __restrict__ hb,
                                                const unsigned short* __restrict__ w5b,
                                                const float* __restrict__ b5,
                                                float* __restrict__ pmax, float* __restrict__ psum){
  __shared__ char sm[20480 + 4096];
  char* As = sm; char* Bs = sm + 10240;
  float* red = (float*)(sm + 20480);
  const int tid = threadIdx.x, lane = tid & 63, w = tid >> 6;
  const int l15 = lane & 15, quad = lane >> 4;
  const int n0 = blockIdx.y*128, r0 = blockIdx.x*128;

  f32x4 acc[2][8];
  f32x4 zero = {0.f,0.f,0.f,0.f};
#pragma unroll
  for (int i = 0; i < 2; i++)
#pragma unroll
    for (int j = 0; j < 8; j++) acc[i][j] = zero;

  for (int k0 = 0; k0 < 512; k0 += 32){
#pragma unroll
    for (int i = 0; i < 2; i++){
      int e = tid + i*256;
      int r = e >> 2, sg = e & 3;
      *(float4*)(As + r*80 + sg*16) = *(const float4*)(hb  + ((size_t)(r0+r))*512 + k0 + sg*8);
      *(float4*)(Bs + r*80 + sg*16) = *(const float4*)(w5b + ((size_t)(n0+r))*512 + k0 + sg*8);
    }
    __syncthreads();
    short8 af0 = *(short8*)(As + (w*32 + l15)*80 + quad*16);
    short8 af1 = *(short8*)(As + (w*32 + 16 + l15)*80 + quad*16);
#pragma unroll
    for (int ns = 0; ns < 8; ns++){
      short8 bf = *(short8*)(Bs + (ns*16 + l15)*80 + quad*16);
      acc[0][ns] = mfma16(af0, bf, acc[0][ns]);
      acc[1][ns] = mfma16(af1, bf, acc[1][ns]);
    }
    __syncthreads();
  }

#pragma unroll
  for (int ns = 0; ns < 8; ns++){
    float bv = b5[n0 + ns*16 + l15];
    float mx = -1e30f, sum = 0.f;
#pragma unroll
    for (int ms = 0; ms < 2; ms++){
      float* a = (float*)&acc[ms][ns];
#pragma unroll
      for (int r = 0; r < 4; r++){
        float v = a[r] + bv; v = fmaxf(v, 0.2f*v);
        mx = fmaxf(mx, v); sum += v;
      }
    }
    for (int s = 16; s < 64; s <<= 1){
      mx = fmaxf(mx, __shfl_xor(mx, s));
      sum += __shfl_xor(sum, s);
    }
    if (quad == 0){ red[(w*8 + ns)*16 + l15] = mx; red[512 + (w*8 + ns)*16 + l15] = sum; }
  }
  __syncthreads();
  if (tid < 128){
    int ns = tid >> 4, ci = tid & 15;
    float mx = -1e30f, sum = 0.f;
#pragma unroll
    for (int w2 = 0; w2 < 4; w2++){
      mx = fmaxf(mx, red[(w2*8 + ns)*16 + ci]);
      sum += red[512 + (w2*8 + ns)*16 + ci];
    }
    pmax[(size_t)blockIdx.x*1024 + n0 + tid] = mx;
    psum[(size_t)blockIdx.x*1024 + n0 + tid] = sum;
  }
}

// ---------------- FC1: 2048->512, pool fused (max/mean over 8 chunks) ----------------
__global__ __launch_bounds__(256) void k_fc1(const float* __restrict__ pmax, const float* __restrict__ psum,
                                             const float* __restrict__ wl1, const float* __restrict__ bn6,
                                             float* __restrict__ h1){
  __shared__ float pS[2048];
  const int b = blockIdx.y, t = threadIdx.x;
  for (int f = t; f < 512; f += 256){
    float4 r;
    if (f < 256){
      r = ld4(pmax + (size_t)(b*8)*1024 + f*4);
#pragma unroll
      for (int ch = 1; ch < 8; ch++) max4(r, ld4(pmax + (size_t)(b*8+ch)*1024 + f*4));
    } else {
      int o = (f-256)*4;
      r = ld4(psum + (size_t)(b*8)*1024 + o);
#pragma unroll
      for (int ch = 1; ch < 8; ch++){
        float4 s = ld4(psum + (size_t)(b*8+ch)*1024 + o);
        r.x += s.x; r.y += s.y; r.z += s.z; r.w += s.w;
      }
      r.x *= (1.f/1024.f); r.y *= (1.f/1024.f); r.z *= (1.f/1024.f); r.w *= (1.f/1024.f);
    }
    ((float4*)pS)[f] = r;
  }
  __syncthreads();
  const int ol = t >> 4, ch = t & 15;
  const int o = blockIdx.x*16 + ol;
  const float* wr = wl1 + (size_t)o*2048;
  float acc = 0.f;
#pragma unroll
  for (int j = 0; j < 32; j++){
    int c = ch*4 + j*64;
    float4 wv = ld4(wr + c);
    acc += pS[c]*wv.x + pS[c+1]*wv.y + pS[c+2]*wv.z + pS[c+3]*wv.w;
  }
#pragma unroll
  for (int s = 1; s < 16; s <<= 1) acc += __shfl_xor(acc, s);
  if (ch == 0){
    float s = bn6[o] * rsqrtf(bn6[3*512+o] + BNEPS);
    float y = (acc - bn6[2*512+o])*s + bn6[512+o];
    h1[(size_t)b*512 + o] = fmaxf(y, 0.2f*y);
  }
}

// ---------------- FC2: 512->256 ----------------
__global__ __launch_bounds__(256) void k_fc2(const float* __restrict__ h1,
                                             const float* __restrict__ wl2, const float* __restrict__ bn7,
                                             float* __restrict__ h2){
  __shared__ float hS[512];
  const int b = blockIdx.y, t = threadIdx.x;
  if (t < 128) ((float4*)hS)[t] = ((const float4*)(h1 + (size_t)b*512))[t];
  __syncthreads();
  const int ol = t >> 4, ch = t & 15;
  const int o = blockIdx.x*16 + ol;
  const float* wr = wl2 + (size_t)o*512;
  float acc = 0.f;
#pragma unroll
  for (int j = 0; j < 8; j++){
    int c = ch*4 + j*64;
    float4 wv = ld4(wr + c);
    acc += hS[c]*wv.x + hS[c+1]*wv.y + hS[c+2]*wv.z + hS[c+3]*wv.w;
  }
#pragma unroll
  for (int s = 1; s < 16; s <<= 1) acc += __shfl_xor(acc, s);
  if (ch == 0){
    float s = bn7[o] * rsqrtf(bn7[3*256+o] + BNEPS);
    float y = (acc - bn7[2*256+o])*s + bn7[256+o];
    h2[(size_t)b*256 + o] = fmaxf(y, 0.2f*y);
  }
}

// ---------------- FC3: 256->40 ----------------
__global__ __launch_bounds__(64) void k_fc3(const float* __restrict__ h2,
                                            const float* __restrict__ wl3, const float* __restrict__ bl3,
                                            float* __restrict__ out){
  const int o = blockIdx.x, b = blockIdx.y, lane = threadIdx.x;
  float4 wv = ld4(wl3 + (size_t)o*256 + lane*4);
  float4 hv = ld4(h2 + (size_t)b*256 + lane*4);
  float acc = hv.x*wv.x + hv.y*wv.y + hv.z*wv.z + hv.w*wv.w;
#pragma unroll
  for (int s = 1; s < 64; s <<= 1) acc += __shfl_xor(acc, s);
  if (lane == 0) out[(size_t)b*40 + o] = acc + bl3[o];
}

extern "C" void kernel_launch(void* const* d_in, const int* in_sizes, int n_in,
                              void* d_out, int out_size, void* d_ws, size_t ws_size,
                              hipStream_t stream) {
  (void)in_sizes; (void)n_in; (void)out_size; (void)ws_size;
  const float* x   = (const float*)d_in[0];
  const float* w1  = (const float*)d_in[1];
  const float* bn1 = (const float*)d_in[2];
  const float* w2  = (const float*)d_in[3];
  const float* bn2 = (const float*)d_in[4];
  const float* w3  = (const float*)d_in[5];
  const float* bn3 = (const float*)d_in[6];
  const float* w4  = (const float*)d_in[7];
  const float* bn4 = (const float*)d_in[8];
  const float* w5  = (const float*)d_in[9];
  const float* bn5 = (const float*)d_in[10];
  const float* wl1 = (const float*)d_in[11];
  const float* bn6 = (const float*)d_in[12];
  const float* wl2 = (const float*)d_in[13];
  const float* bn7 = (const float*)d_in[14];
  const float* wl3 = (const float*)d_in[15];
  const float* bl3 = (const float*)d_in[16];
  float* out = (float*)d_out;

  // workspace layout byte-identical to the verified round-3 kernel (no growth);
  // pd slot now only used as Z (uv output); fused pd+topk keeps pd in LDS.
  float* ws    = (float*)d_ws;
  float* xt    = ws;                          // 65536
  float* sqb   = xt + 65536;                  // 16384
  int*   idxb  = (int*)(sqb + 16384);         // 327680 ints
  float* pd    = (float*)(idxb + 327680);     // 16777216 (Z lives here)
  unsigned short* hlo = (unsigned short*)(pd + 16777216); // 8388608 ushorts (old h slot, same bytes)
  float* wlT1  = (float*)(hlo + 8388608);     // 256
  float* dT1   = wlT1 + 256;                  // 256
  float* bias1 = dT1 + 256;                   // 64
  float* bias2 = bias1 + 64;                  // 64
  float* bias3 = bias2 + 64;                  // 128
  float* bias4 = bias3 + 128;                 // 256
  float* b5    = bias4 + 256;                 // 1024
  float* pmax  = b5 + 1024;                   // 131072
  float* psum  = pmax + 131072;               // 131072
  float* pool  = psum + 131072;               // 32768 (unused; layout kept)
  float* h1b   = pool + 32768;                // 8192
  float* h2b   = h1b + 8192;                  // 4096
  unsigned short* hb   = (unsigned short*)(h2b + 4096);    // 16384*512 bf16
  unsigned short* wlB2 = hb + (size_t)16384*512;            // 4096 (dB2 contiguous after)
  unsigned short* dB2  = wlB2 + 4096;
  unsigned short* wlB3 = dB2 + 4096;                        // 8192 (dB3 contiguous)
  unsigned short* dB3  = wlB3 + 8192;
  unsigned short* wlB4 = dB3 + 8192;                        // 32768 (dB4 contiguous)
  unsigned short* dB4  = wlB4 + 32768;
  unsigned short* w5b  = dB4 + 32768;                       // 524288
  float* Z = pd;

  k_transpose<<<64, 256, 0, stream>>>(x, xt, hlo, sqb);
  k_prep_all<<<2225, 256, 0, stream>>>(w1, bn1, w2, bn2, w3, bn3, w4, bn4, w5, bn5,
                                       wlT1, dT1, bias1, wlB2, dB2, bias2,
                                       wlB3, dB3, bias3, wlB4, dB4, bias4, w5b, b5);

  // ---- L1 (Cin=3 -> Cout=64) ----
  k_pdtopk1<<<1024, 256, 0, stream>>>(hlo, sqb, idxb);
  k_uv1<<<2048, 256, 0, stream>>>(xt, wlT1, dT1, Z);
  k_gmax<64,16,true><<<1024, 256, 0, stream>>>(Z, bias1, idxb, hb, hlo);

  // ---- L2 (64 -> 64) ----
  k_sqb<64><<<64, 256, 0, stream>>>(hb, hlo, sqb);
  k_pdtopk<64><<<1024, 256, 0, stream>>>(hb, hlo, sqb, idxb);
  k_uv<64><<<dim3(128,1), 256, 0, stream>>>(hb, wlB2, Z, 128);
  k_gmax<64,16,true><<<1024, 256, 0, stream>>>(Z, bias2, idxb, hb + 64, hlo + 64);

  // ---- L3 (64 -> 128) ----
  k_sqb<64><<<64, 256, 0, stream>>>(hb + 64, hlo + 64, sqb);
  k_pdtopk<64><<<1024, 256, 0, stream>>>(hb + 64, hlo + 64, sqb, idxb);
  k_uv<64><<<dim3(128,2), 256, 0, stream>>>(hb + 64, wlB3, Z, 256);
  k_gmax<128,8,true><<<2048, 256, 0, stream>>>(Z, bias3, idxb, hb + 128, hlo + 128);

  // ---- L4 (128 -> 256; bf16 out only) ----
  k_sqb<128><<<64, 256, 0, stream>>>(hb + 128, hlo + 128, sqb);
  k_pdtopk<128><<<1024, 256, 0, stream>>>(hb + 128, hlo + 128, sqb, idxb);
  k_uv<128><<<dim3(128,4), 256, 0, stream>>>(hb + 128, wlB4, Z, 512);
  k_gmax<256,4,false><<<4096, 256, 0, stream>>>(Z, bias4, idxb, hb + 256, nullptr);

  // ---- conv5 + FC head (pool fused into fc1) ----
  k_conv5m<<<dim3(128,8), 256, 0, stream>>>(hb, w5b, b5, pmax, psum);
  k_fc1<<<dim3(32,16), 256, 0, stream>>>(pmax, psum, wl1, bn6, h1b);
  k_fc2<<<dim3(16,16), 256, 0, stream>>>(h1b, wl2, bn7, h2b);
  k_fc3<<<dim3(40,16), 64, 0, stream>>>(h2b, wl3, bl3, out);
}

// Round 10
// 422.077 us; speedup vs baseline: 1.1808x; 1.1808x over previous
//
#include <hip/hip_runtime.h>

#define BB 16
#define NN 1024
#define KNN 20
#define BNEPS 1e-5f

typedef __attribute__((ext_vector_type(8))) short short8;
typedef __attribute__((ext_vector_type(4))) float f32x4;

__device__ __forceinline__ float4 ld4(const float* p){ return *(const float4*)p; }
__device__ __forceinline__ void fma4(float4& a, float s, float4 w){
  a.x = fmaf(s, w.x, a.x); a.y = fmaf(s, w.y, a.y);
  a.z = fmaf(s, w.z, a.z); a.w = fmaf(s, w.w, a.w);
}
__device__ __forceinline__ void max4(float4& a, float4 v){
  a.x = fmaxf(a.x, v.x); a.y = fmaxf(a.y, v.y);
  a.z = fmaxf(a.z, v.z); a.w = fmaxf(a.w, v.w);
}
__device__ __forceinline__ unsigned short f2bf(float f){
  unsigned int u = __float_as_uint(f);
  u = (u + 0x7FFF + ((u >> 16) & 1)) >> 16;   // RNE, finite inputs
  return (unsigned short)u;
}
__device__ __forceinline__ float bf2f(unsigned short u){
  return __uint_as_float(((unsigned int)u) << 16);
}
__device__ __forceinline__ f32x4 mfma16(short8 a, short8 b, f32x4 c){
  return __builtin_amdgcn_mfma_f32_16x16x32_bf16(a, b, c, 0, 0, 0);
}

// build exact (value desc, index asc) top-3 of a lane's 16 row elements, excluding km bits
__device__ __forceinline__ void top3_build(const float* rp, int kmr,
                                           float& a0, float& a1, float& a2,
                                           int& i0, int& i1, int& i2){
  a0 = -1e30f; a1 = -1e30f; a2 = -1e30f; i0 = 0; i1 = 0; i2 = 0;
#pragma unroll
  for (int r = 0; r < 4; r++){
    float4 t = ld4(rp + r*4);
    float tv[4] = {t.x, t.y, t.z, t.w};
#pragma unroll
    for (int q = 0; q < 4; q++){
      int e = r*4 + q;
      float v = ((kmr >> e) & 1) ? -1e30f : tv[q];
      bool b0 = v > a0, b1 = v > a1, b2 = v > a2;
      a2 = b1 ? a1 : (b2 ? v : a2); i2 = b1 ? i1 : (b2 ? e : i2);
      a1 = b0 ? a0 : (b1 ? v : a1); i1 = b0 ? i0 : (b1 ? e : i1);
      a0 = b0 ? v  : a0;            i0 = b0 ? e : i0;
    }
  }
}

// ---- transpose x (B,3,N) -> xt (B,N,4) fp32 (for uv1); packed split-bf16 MFMA operands
//      embedded in hlo's unused channel space (per-row: A at +256, B at +288, 32 shorts each)
//      A = [hi|lo|hi|0..] (K=32), B = [hi|hi|lo|0..]; sq from hi+lo for consistency ----
__global__ __launch_bounds__(256) void k_transpose(const float* __restrict__ x, float* __restrict__ xt,
                                                   unsigned short* __restrict__ hlo,
                                                   float* __restrict__ sq){
  int i = blockIdx.x*256 + threadIdx.x;
  if (i >= BB*NN) return;
  int b = i >> 10, n = i & 1023;
  const float* xb = x + (size_t)b*3*NN;
  float4 v;
  v.x = xb[0*NN+n]; v.y = xb[1*NN+n]; v.z = xb[2*NN+n]; v.w = 0.f;
  ((float4*)xt)[i] = v;
  unsigned short hx = f2bf(v.x), hy = f2bf(v.y), hz = f2bf(v.z);
  float rx = v.x - bf2f(hx), ry = v.y - bf2f(hy), rz = v.z - bf2f(hz);
  unsigned short lx = f2bf(rx), ly = f2bf(ry), lz = f2bf(rz);
  float ex = bf2f(hx)+bf2f(lx), ey = bf2f(hy)+bf2f(ly), ez = bf2f(hz)+bf2f(lz);
  sq[i] = ex*ex + ey*ey + ez*ez;          // consistent with Gram inputs
  ushort4 h4 = {hx, hy, hz, 0};
  ushort4 l4 = {lx, ly, lz, 0};
  ushort4 z4 = {0, 0, 0, 0};
  unsigned short* pa = hlo + (size_t)i*512 + 256;
  unsigned short* pb = hlo + (size_t)i*512 + 288;
  *(ushort4*)(pa+0) = h4; *(ushort4*)(pa+4) = l4; *(ushort4*)(pa+8) = h4;
  *(ushort4*)(pb+0) = h4; *(ushort4*)(pb+4) = h4; *(ushort4*)(pb+8) = l4;
#pragma unroll
  for (int s = 12; s < 32; s += 4){ *(ushort4*)(pa+s) = z4; *(ushort4*)(pb+s) = z4; }
}

// ---- device preps ----
__device__ __forceinline__ void prep_w_dev(int i, const float* w, const float* bnp,
                                           float* wlT, float* dT, float* bias, int Cin, int Cpad, int Cout){
  if (i >= Cpad*Cout) return;
  int c = i / Cout, o = i - c*Cout;
  float s = bnp[o] * rsqrtf(bnp[3*Cout+o] + BNEPS);
  float wl = (c < Cin) ? w[(size_t)o*2*Cin + c] : 0.f;
  float wr = (c < Cin) ? w[(size_t)o*2*Cin + Cin + c] : 0.f;
  wlT[i] = wl * s;
  dT[i]  = (wr - wl) * s;
  if (c == 0) bias[o] = bnp[Cout+o] - bnp[2*Cout+o]*s;
}
__device__ __forceinline__ void prep_wbf_dev(int i, const float* w, const float* bnp,
                                             unsigned short* wlB, unsigned short* dB, float* bias,
                                             int Cin, int Cout){
  if (i >= Cin*Cout) return;
  int o = i / Cin, c = i - o*Cin;
  float s = bnp[o] * rsqrtf(bnp[3*Cout+o] + BNEPS);
  float wl = w[(size_t)o*2*Cin + c] * s;
  float wr = w[(size_t)o*2*Cin + Cin + c] * s;
  wlB[i] = f2bf(wl);
  dB[i]  = f2bf(wr - wl);
  if (c == 0) bias[o] = bnp[Cout+o] - bnp[2*Cout+o]*s;
}

// ---- single merged prep kernel ----
__global__ __launch_bounds__(256) void k_prep_all(const float* __restrict__ w1, const float* __restrict__ bn1,
                                                  const float* __restrict__ w2, const float* __restrict__ bn2,
                                                  const float* __restrict__ w3, const float* __restrict__ bn3,
                                                  const float* __restrict__ w4, const float* __restrict__ bn4,
                                                  const float* __restrict__ w5, const float* __restrict__ bn5,
                                                  float* __restrict__ wlT1, float* __restrict__ dT1, float* __restrict__ bias1,
                                                  unsigned short* __restrict__ wlB2, unsigned short* __restrict__ dB2, float* __restrict__ bias2,
                                                  unsigned short* __restrict__ wlB3, unsigned short* __restrict__ dB3, float* __restrict__ bias3,
                                                  unsigned short* __restrict__ wlB4, unsigned short* __restrict__ dB4, float* __restrict__ bias4,
                                                  unsigned short* __restrict__ w5b, float* __restrict__ b5){
  int bid = blockIdx.x, t = threadIdx.x;
  if (bid < 1){
    prep_w_dev(t, w1, bn1, wlT1, dT1, bias1, 3, 4, 64);
  } else if (bid < 17){
    prep_wbf_dev((bid-1)*256 + t, w2, bn2, wlB2, dB2, bias2, 64, 64);
  } else if (bid < 49){
    prep_wbf_dev((bid-17)*256 + t, w3, bn3, wlB3, dB3, bias3, 64, 128);
  } else if (bid < 177){
    prep_wbf_dev((bid-49)*256 + t, w4, bn4, wlB4, dB4, bias4, 128, 256);
  } else {
    int i = (bid-177)*256 + t;
    int o = i >> 9, c = i & 511;
    float s = bn5[o] * rsqrtf(bn5[3*1024+o] + BNEPS);
    w5b[i] = f2bf(w5[(size_t)o*512 + c] * s);
    if (c == 0) b5[o] = bn5[1024+o] - bn5[2*1024+o]*s;
  }
}

// -------- pd via split-bf16 MFMA Gram (fp32-equivalent: hi*hi + lo*hi + hi*lo) --------
// 1D grid 1024, XCD swizzle: bid&7 = XCD, batches {c, c+8} pinned per XCD so the
// batch's A/B panels are fetched once into the local L2 and pd writes stay local.
// Epilogue staged through LDS: 256B-contiguous float4 row segments (full 128B lines).
template<int CC>
__global__ __launch_bounds__(256) void k_pdm(const unsigned short* __restrict__ hbi,
                                             const unsigned short* __restrict__ hlo,
                                             const float* __restrict__ sq,
                                             float* __restrict__ pd){
  __shared__ char sm[20480];
  char* As = sm; char* Bs = sm + 10240;
  const int tid = threadIdx.x, lane = tid & 63, w = tid >> 6;
  const int l15 = lane & 15, quad = lane >> 4;
  const int bid = blockIdx.x;
  const int xcd = bid & 7, j = bid >> 3;
  const int b = xcd + ((j >> 6) << 3);
  const int rt = (j >> 3) & 7, ct = j & 7;
  const size_t ar0 = (size_t)b*NN + rt*128;             // A global rows
  const size_t br0 = (size_t)b*NN + ct*128;             // B global rows (pd col base)
  const int colb = ct*128;

  f32x4 acc[2][8];
  f32x4 zero = {0.f,0.f,0.f,0.f};
#pragma unroll
  for (int i = 0; i < 2; i++)
#pragma unroll
    for (int j2 = 0; j2 < 8; j2++) acc[i][j2] = zero;

  for (int k0 = 0; k0 < 3*CC; k0 += 32){
    int seg = k0 / CC, off = k0 - seg*CC;
    const unsigned short* Ap = (seg == 1) ? hlo : hbi;  // hi, lo, hi
    const unsigned short* Bp = (seg == 2) ? hlo : hbi;  // hi, hi, lo
#pragma unroll
    for (int i = 0; i < 2; i++){
      int e = tid + i*256;
      int r = e >> 2, sg = e & 3;
      *(float4*)(As + r*80 + sg*16) = *(const float4*)(Ap + (ar0+r)*512 + off + sg*8);
      *(float4*)(Bs + r*80 + sg*16) = *(const float4*)(Bp + (br0+r)*512 + off + sg*8);
    }
    __syncthreads();
    short8 af0 = *(short8*)(As + (w*32 + l15)*80 + quad*16);
    short8 af1 = *(short8*)(As + (w*32 + 16 + l15)*80 + quad*16);
#pragma unroll
    for (int ns = 0; ns < 8; ns++){
      short8 bf = *(short8*)(Bs + (ns*16 + l15)*80 + quad*16);
      acc[0][ns] = mfma16(af0, bf, acc[0][ns]);
      acc[1][ns] = mfma16(af1, bf, acc[1][ns]);
    }
    __syncthreads();
  }

  // epilogue: 4 passes (ms, nh); stage 64 rows x 64 cols, store 256B/row full lines
  float* L = (float*)sm;
#pragma unroll
  for (int p = 0; p < 4; p++){
    const int ms = p >> 1, nh = p & 1;
    __syncthreads();
#pragma unroll
    for (int ns = 0; ns < 4; ns++){
      f32x4 a = acc[ms][nh*4 + ns];
      float sqv = sq[br0 + (nh*4+ns)*16 + l15];
#pragma unroll
      for (int r = 0; r < 4; r++)
        L[(w*16 + quad*4 + r)*68 + ns*16 + l15] = 2.f*a[r] - sqv;
    }
    __syncthreads();
#pragma unroll
    for (int k = 0; k < 4; k++){
      int e = tid + k*256;
      int lr = e >> 4, c4 = (e & 15)*4;
      int grow = (int)ar0 + (lr >> 4)*32 + ms*16 + (lr & 15);
      *(float4*)(pd + (size_t)grow*NN + colb + nh*64 + c4) = *(float4*)(L + lr*68 + c4);
    }
  }
}

// -------- L1 pd: packed K=32 operands embedded in hlo (row*512+256 / +288), one MFMA step ----
__global__ __launch_bounds__(256) void k_pdm1(const unsigned short* __restrict__ hlo,
                                              const float* __restrict__ sq,
                                              float* __restrict__ pd){
  __shared__ char sm[20480];
  char* As = sm; char* Bs = sm + 10240;
  const int tid = threadIdx.x, lane = tid & 63, w = tid >> 6;
  const int l15 = lane & 15, quad = lane >> 4;
  const int bid = blockIdx.x;
  const int xcd = bid & 7, j = bid >> 3;
  const int b = xcd + ((j >> 6) << 3);
  const int rt = (j >> 3) & 7, ct = j & 7;
  const size_t ar0 = (size_t)b*NN + rt*128;
  const size_t br0 = (size_t)b*NN + ct*128;
  const int colb = ct*128;

#pragma unroll
  for (int i = 0; i < 2; i++){
    int e = tid + i*256;
    int r = e >> 2, sg = e & 3;
    *(float4*)(As + r*80 + sg*16) = *(const float4*)(hlo + (ar0+r)*512 + 256 + sg*8);
    *(float4*)(Bs + r*80 + sg*16) = *(const float4*)(hlo + (br0+r)*512 + 288 + sg*8);
  }
  __syncthreads();

  f32x4 acc[2][8];
  f32x4 zero = {0.f,0.f,0.f,0.f};
#pragma unroll
  for (int i = 0; i < 2; i++)
#pragma unroll
    for (int j2 = 0; j2 < 8; j2++) acc[i][j2] = zero;

  short8 af0 = *(short8*)(As + (w*32 + l15)*80 + quad*16);
  short8 af1 = *(short8*)(As + (w*32 + 16 + l15)*80 + quad*16);
#pragma unroll
  for (int ns = 0; ns < 8; ns++){
    short8 bf = *(short8*)(Bs + (ns*16 + l15)*80 + quad*16);
    acc[0][ns] = mfma16(af0, bf, acc[0][ns]);
    acc[1][ns] = mfma16(af1, bf, acc[1][ns]);
  }

  // epilogue identical to k_pdm (LDS reuse is safe: sync at each pass head)
  float* L = (float*)sm;
#pragma unroll
  for (int p = 0; p < 4; p++){
    const int ms = p >> 1, nh = p & 1;
    __syncthreads();
#pragma unroll
    for (int ns = 0; ns < 4; ns++){
      f32x4 a = acc[ms][nh*4 + ns];
      float sqv = sq[br0 + (nh*4+ns)*16 + l15];
#pragma unroll
      for (int r = 0; r < 4; r++)
        L[(w*16 + quad*4 + r)*68 + ns*16 + l15] = 2.f*a[r] - sqv;
    }
    __syncthreads();
#pragma unroll
    for (int k = 0; k < 4; k++){
      int e = tid + k*256;
      int lr = e >> 4, c4 = (e & 15)*4;
      int grow = (int)ar0 + (lr >> 4)*32 + ms*16 + (lr & 15);
      *(float4*)(pd + (size_t)grow*NN + colb + nh*64 + c4) = *(float4*)(L + lr*68 + c4);
    }
  }
}

// ------------ top-k v5 (k=20): per-lane sorted top-3 cache, 2 rows/wave ------------
// XCD swizzle matched to k_pdm: rows of batch b are read on XCD b&7, where pd was written.
__global__ __launch_bounds__(256) void k_topk(const float* __restrict__ pd, int* __restrict__ idxOut){
  int w = threadIdx.x >> 6, lane = threadIdx.x & 63;
  const int bid = blockIdx.x;
  const int xcd = bid & 7, j = bid >> 3;            // j 0..255
  const int b = xcd + ((j >> 7) << 3);
  const int local = j & 127;
  int bn0 = (b*128 + local)*8 + w*2;
  const float* row0 = pd + (size_t)bn0*NN + lane*16;
  const float* row1 = row0 + NN;

  float c0v[2], c1v[2], c2v[2];
  int   c0i[2], c1i[2], c2i[2];
  int   km[2] = {0, 0};
  top3_build(row0, 0, c0v[0], c1v[0], c2v[0], c0i[0], c1i[0], c2i[0]);
  top3_build(row1, 0, c0v[1], c1v[1], c2v[1], c0i[1], c1i[1], c2i[1]);

  int* out0 = idxOut + (size_t)bn0*KNN;
  int* out1 = out0 + KNN;
  for (int it = 0; it < KNN; it++){
    float g0 = c0v[0], g1 = c0v[1];
#pragma unroll
    for (int s = 1; s < 64; s <<= 1){
      g0 = fmaxf(g0, __shfl_xor(g0, s));
      g1 = fmaxf(g1, __shfl_xor(g1, s));
    }
    int o0 = __ffsll(__ballot(c0v[0] == g0)) - 1;
    int o1 = __ffsll(__ballot(c0v[1] == g1)) - 1;
    bool u0 = (lane == o0), u1 = (lane == o1);
    if (u0) out0[it] = lane*16 + c0i[0];
    if (u1) out1[it] = lane*16 + c0i[1];
    km[0] |= u0 ? (1 << c0i[0]) : 0;
    km[1] |= u1 ? (1 << c0i[1]) : 0;
    c0v[0] = u0 ? c1v[0] : c0v[0];  c0i[0] = u0 ? c1i[0] : c0i[0];
    c1v[0] = u0 ? c2v[0] : c1v[0];  c1i[0] = u0 ? c2i[0] : c1i[0];
    c2v[0] = u0 ? -1e30f : c2v[0];
    c0v[1] = u1 ? c1v[1] : c0v[1];  c0i[1] = u1 ? c1i[1] : c0i[1];
    c1v[1] = u1 ? c2v[1] : c1v[1];  c1i[1] = u1 ? c2i[1] : c1i[1];
    c2v[1] = u1 ? -1e30f : c2v[1];
    if (it < KNN-1){
      bool rp0 = (c0v[0] == -1e30f) && (km[0] != 0xFFFF);
      bool rp1 = (c0v[1] == -1e30f) && (km[1] != 0xFFFF);
      if (__ballot(rp0 || rp1)){
        if (rp0) top3_build(row0, km[0], c0v[0], c1v[0], c2v[0], c0i[0], c1i[0], c2i[0]);
        if (rp1) top3_build(row1, km[1], c0v[1], c1v[1], c2v[1], c0i[1], c1i[1], c2i[1]);
      }
    }
  }
}

// ---------------- L1 U|V: Z[n][0..63]=xt_n*wlT1, Z[n][64..127]=xt_n*dT1 (fp32, K=4) --------
// block swizzle: 128 blocks/batch pinned to xcd = batch&7 (matches gmax/pdm locality)
__global__ __launch_bounds__(256) void k_uv1(const float* __restrict__ xt,
                                             const float* __restrict__ wlT, const float* __restrict__ dT,
                                             float* __restrict__ Z){
  const int bid = blockIdx.x;    // 2048 blocks
  const int pb = ((bid >> 10) << 10) | ((bid & 7) << 7) | ((bid >> 3) & 127);
  int t = pb*256 + threadIdx.x;
  int n = t >> 5, q = t & 31;
  float4 xv = ld4(xt + (size_t)n*4);
  const float* wp = (q < 16) ? (wlT + q*4) : (dT + (q-16)*4);
  float4 a = make_float4(0.f,0.f,0.f,0.f);
  fma4(a, xv.x, ld4(wp + 0*64));
  fma4(a, xv.y, ld4(wp + 1*64));
  fma4(a, xv.z, ld4(wp + 2*64));
  fma4(a, xv.w, ld4(wp + 3*64));
  *(float4*)(Z + (size_t)n*128 + q*4) = a;
}

// ---------------- U|V dense GEMM (bf16 MFMA) ----------------
// grid: x = data-row tile, swizzled so batch b's 8 row-tiles land on xcd b&7
// (shares the A panel on one L2 AND makes Z writes batch->xcd local for gmax)
template<int K>
__global__ __launch_bounds__(256) void k_uv(const unsigned short* __restrict__ hbi,
                                            const unsigned short* __restrict__ wB,
                                            float* __restrict__ Z, int ldz){
  __shared__ char sm[20480];
  char* As = sm; char* Bs = sm + 10240;
  const int tid = threadIdx.x, lane = tid & 63, w = tid >> 6;
  const int l15 = lane & 15, quad = lane >> 4;
  const int bx = blockIdx.x;     // 128 row-tiles
  const int t = ((bx & 7) << 3) | ((bx >> 3) & 7) | (bx & 64);
  const int n0 = blockIdx.y*128, r0 = t*128;

  f32x4 acc[2][8];
  f32x4 zero = {0.f,0.f,0.f,0.f};
#pragma unroll
  for (int i = 0; i < 2; i++)
#pragma unroll
    for (int j = 0; j < 8; j++) acc[i][j] = zero;

  for (int k0 = 0; k0 < K; k0 += 32){
#pragma unroll
    for (int i = 0; i < 2; i++){
      int e = tid + i*256;
      int r = e >> 2, sg = e & 3;
      *(float4*)(As + r*80 + sg*16) = *(const float4*)(hbi + ((size_t)(r0+r))*512 + k0 + sg*8);
      *(float4*)(Bs + r*80 + sg*16) = *(const float4*)(wB  + ((size_t)(n0+r))*K   + k0 + sg*8);
    }
    __syncthreads();
    short8 af0 = *(short8*)(As + (w*32 + l15)*80 + quad*16);
    short8 af1 = *(short8*)(As + (w*32 + 16 + l15)*80 + quad*16);
#pragma unroll
    for (int ns = 0; ns < 8; ns++){
      short8 bf = *(short8*)(Bs + (ns*16 + l15)*80 + quad*16);
      acc[0][ns] = mfma16(af0, bf, acc[0][ns]);
      acc[1][ns] = mfma16(af1, bf, acc[1][ns]);
    }
    __syncthreads();
  }

#pragma unroll
  for (int ms = 0; ms < 2; ms++){
#pragma unroll
    for (int ns = 0; ns < 8; ns++){
      f32x4 a = acc[ms][ns];
      int row = r0 + w*32 + ms*16 + quad*4;
      int col = n0 + ns*16 + l15;
#pragma unroll
      for (int r = 0; r < 4; r++)
        Z[(size_t)(row+r)*ldz + col] = a[r];
    }
  }
}

// ---------------- gather-max: emits bf16 hi (hb), bf16 lo (hlo), and fused sq ----------------
// block swizzle: blocks of batch b pinned to xcd b&7 (Z gather + hb/hlo writes L2-local).
// sq = sum over this layer's channels of (bf2f(hi)+bf2f(lo))^2 — replaces k_sqb (WLO layers).
template<int COUT, int P, bool WLO>
__global__ __launch_bounds__(256) void k_gmax(const float* __restrict__ Z,
                                              const float* __restrict__ bias,
                                              const int* __restrict__ knn_idx,
                                              unsigned short* __restrict__ hbo,
                                              unsigned short* __restrict__ hloo,
                                              float* __restrict__ sqo){
  constexpr int QPP = COUT/4;
  constexpr int BPB = 1024/P;                      // blocks per batch
  constexpr int SHF = (P == 16) ? 6 : (P == 8) ? 7 : 8;
  __shared__ int idxS[P*KNN];
  const int tid = threadIdx.x;
  const int bid = blockIdx.x;
  const int pb = ((bid >> (SHF+3)) << (SHF+3)) | ((bid & 7) << SHF) | ((bid >> 3) & (BPB-1));
  const int p0 = pb * P;
  for (int t = tid; t < P*KNN; t += 256) idxS[t] = knn_idx[(size_t)p0*KNN + t];
  __syncthreads();

  const int p = tid / QPP, q = tid - p*QPP;
  const int base = p0 & ~1023;
  const int ldz = 2*COUT;
  const float* Zq = Z + q*4;

  float4 m = make_float4(-1e30f,-1e30f,-1e30f,-1e30f);
#pragma unroll
  for (int j = 0; j < KNN; j++){
    int mr = idxS[p*KNN + j];
    max4(m, ld4(Zq + (size_t)(base + mr)*ldz));
  }
  float4 ctr = ld4(Z + (size_t)(p0+p)*ldz + COUT + q*4);
  float4 bs  = ld4(bias + q*4);
  float4 y;
  y.x = m.x + ctr.x + bs.x; y.x = fmaxf(y.x, 0.2f*y.x);
  y.y = m.y + ctr.y + bs.y; y.y = fmaxf(y.y, 0.2f*y.y);
  y.z = m.z + ctr.z + bs.z; y.z = fmaxf(y.z, 0.2f*y.z);
  y.w = m.w + ctr.w + bs.w; y.w = fmaxf(y.w, 0.2f*y.w);

  size_t pi = (size_t)(p0 + p);
  ushort4 hv; hv.x = f2bf(y.x); hv.y = f2bf(y.y); hv.z = f2bf(y.z); hv.w = f2bf(y.w);
  *(ushort4*)(hbo + pi*512 + q*4) = hv;
  if (WLO){
    ushort4 lv;
    lv.x = f2bf(y.x - bf2f(hv.x)); lv.y = f2bf(y.y - bf2f(hv.y));
    lv.z = f2bf(y.z - bf2f(hv.z)); lv.w = f2bf(y.w - bf2f(hv.w));
    *(ushort4*)(hloo + pi*512 + q*4) = lv;
    // fused sq (matches k_sqb arithmetic exactly)
    float ex = bf2f(hv.x)+bf2f(lv.x), ey = bf2f(hv.y)+bf2f(lv.y);
    float ez = bf2f(hv.z)+bf2f(lv.z), ew = bf2f(hv.w)+bf2f(lv.w);
    float s4 = ex*ex + ey*ey + ez*ez + ew*ew;
#pragma unroll
    for (int sh = 1; sh < QPP; sh <<= 1) s4 += __shfl_xor(s4, sh);
    if (q == 0) sqo[pi] = s4;
  }
}

// ---------------- conv5 (bf16 MFMA) + bias + lrelu + partial pool ----------------
// grid: x = data-row tile (XCD locality for hb panel), y = output-channel tile
__global__ __launch_bounds__(256) void k_conv5m(const unsigned short* __restrict__ hb,
                                                const unsigned short* __restrict__ w5b,
                                                const float* __restrict__ b5,
                                                float* __restrict__ pmax, float* __restrict__ psum){
  __shared__ char sm[20480 + 4096];
  char* As = sm; char* Bs = sm + 10240;
  float* red = (float*)(sm + 20480);
  const int tid = threadIdx.x, lane = tid & 63, w = tid >> 6;
  const int l15 = lane & 15, quad = lane >> 4;
  const int n0 = blockIdx.y*128, r0 = blockIdx.x*128;

  f32x4 acc[2][8];
  f32x4 zero = {0.f,0.f,0.f,0.f};
#pragma unroll
  for (int i = 0; i < 2; i++)
#pragma unroll
    for (int j = 0; j < 8; j++) acc[i][j] = zero;

  for (int k0 = 0; k0 < 512; k0 += 32){
#pragma unroll
    for (int i = 0; i < 2; i++){
      int e = tid + i*256;
      int r = e >> 2, sg = e & 3;
      *(float4*)(As + r*80 + sg*16) = *(const float4*)(hb  + ((size_t)(r0+r))*512 + k0 + sg*8);
      *(float4*)(Bs + r*80 + sg*16) = *(const float4*)(w5b + ((size_t)(n0+r))*512 + k0 + sg*8);
    }
    __syncthreads();
    short8 af0 = *(short8*)(As + (w*32 + l15)*80 + quad*16);
    short8 af1 = *(short8*)(As + (w*32 + 16 + l15)*80 + quad*16);
#pragma unroll
    for (int ns = 0; ns < 8; ns++){
      short8 bf = *(short8*)(Bs + (ns*16 + l15)*80 + quad*16);
      acc[0][ns] = mfma16(af0, bf, acc[0][ns]);
      acc[1][ns] = mfma16(af1, bf, acc[1][ns]);
    }
    __syncthreads();
  }

#pragma unroll
  for (int ns = 0; ns < 8; ns++){
    float bv = b5[n0 + ns*16 + l15];
    float mx = -1e30f, sum = 0.f;
#pragma unroll
    for (int ms = 0; ms < 2; ms++){
      float* a = (float*)&acc[ms][ns];
#pragma unroll
      for (int r = 0; r < 4; r++){
        float v = a[r] + bv; v = fmaxf(v, 0.2f*v);
        mx = fmaxf(mx, v); sum += v;
      }
    }
    for (int s = 16; s < 64; s <<= 1){
      mx = fmaxf(mx, __shfl_xor(mx, s));
      sum += __shfl_xor(sum, s);
    }
    if (quad == 0){ red[(w*8 + ns)*16 + l15] = mx; red[512 + (w*8 + ns)*16 + l15] = sum; }
  }
  __syncthreads();
  if (tid < 128){
    int ns = tid >> 4, ci = tid & 15;
    float mx = -1e30f, sum = 0.f;
#pragma unroll
    for (int w2 = 0; w2 < 4; w2++){
      mx = fmaxf(mx, red[(w2*8 + ns)*16 + ci]);
      sum += red[512 + (w2*8 + ns)*16 + ci];
    }
    pmax[(size_t)blockIdx.x*1024 + n0 + tid] = mx;
    psum[(size_t)blockIdx.x*1024 + n0 + tid] = sum;
  }
}

// ---------------- FC1: 2048->512, pool fused (max/mean over 8 chunks) ----------------
__global__ __launch_bounds__(256) void k_fc1(const float* __restrict__ pmax, const float* __restrict__ psum,
                                             const float* __restrict__ wl1, const float* __restrict__ bn6,
                                             float* __restrict__ h1){
  __shared__ float pS[2048];
  const int b = blockIdx.y, t = threadIdx.x;
  for (int f = t; f < 512; f += 256){
    float4 r;
    if (f < 256){
      r = ld4(pmax + (size_t)(b*8)*1024 + f*4);
#pragma unroll
      for (int ch = 1; ch < 8; ch++) max4(r, ld4(pmax + (size_t)(b*8+ch)*1024 + f*4));
    } else {
      int o = (f-256)*4;
      r = ld4(psum + (size_t)(b*8)*1024 + o);
#pragma unroll
      for (int ch = 1; ch < 8; ch++){
        float4 s = ld4(psum + (size_t)(b*8+ch)*1024 + o);
        r.x += s.x; r.y += s.y; r.z += s.z; r.w += s.w;
      }
      r.x *= (1.f/1024.f); r.y *= (1.f/1024.f); r.z *= (1.f/1024.f); r.w *= (1.f/1024.f);
    }
    ((float4*)pS)[f] = r;
  }
  __syncthreads();
  const int ol = t >> 4, ch = t & 15;
  const int o = blockIdx.x*16 + ol;
  const float* wr = wl1 + (size_t)o*2048;
  float acc = 0.f;
#pragma unroll
  for (int j = 0; j < 32; j++){
    int c = ch*4 + j*64;
    float4 wv = ld4(wr + c);
    acc += pS[c]*wv.x + pS[c+1]*wv.y + pS[c+2]*wv.z + pS[c+3]*wv.w;
  }
#pragma unroll
  for (int s = 1; s < 16; s <<= 1) acc += __shfl_xor(acc, s);
  if (ch == 0){
    float s = bn6[o] * rsqrtf(bn6[3*512+o] + BNEPS);
    float y = (acc - bn6[2*512+o])*s + bn6[512+o];
    h1[(size_t)b*512 + o] = fmaxf(y, 0.2f*y);
  }
}

// ---------------- FC2: 512->256 ----------------
__global__ __launch_bounds__(256) void k_fc2(const float* __restrict__ h1,
                                             const float* __restrict__ wl2, const float* __restrict__ bn7,
                                             float* __restrict__ h2){
  __shared__ float hS[512];
  const int b = blockIdx.y, t = threadIdx.x;
  if (t < 128) ((float4*)hS)[t] = ((const float4*)(h1 + (size_t)b*512))[t];
  __syncthreads();
  const int ol = t >> 4, ch = t & 15;
  const int o = blockIdx.x*16 + ol;
  const float* wr = wl2 + (size_t)o*512;
  float acc = 0.f;
#pragma unroll
  for (int j = 0; j < 8; j++){
    int c = ch*4 + j*64;
    float4 wv = ld4(wr + c);
    acc += hS[c]*wv.x + hS[c+1]*wv.y + hS[c+2]*wv.z + hS[c+3]*wv.w;
  }
#pragma unroll
  for (int s = 1; s < 16; s <<= 1) acc += __shfl_xor(acc, s);
  if (ch == 0){
    float s = bn7[o] * rsqrtf(bn7[3*256+o] + BNEPS);
    float y = (acc - bn7[2*256+o])*s + bn7[256+o];
    h2[(size_t)b*256 + o] = fmaxf(y, 0.2f*y);
  }
}

// ---------------- FC3: 256->40 ----------------
__global__ __launch_bounds__(64) void k_fc3(const float* __restrict__ h2,
                                            const float* __restrict__ wl3, const float* __restrict__ bl3,
                                            float* __restrict__ out){
  const int o = blockIdx.x, b = blockIdx.y, lane = threadIdx.x;
  float4 wv = ld4(wl3 + (size_t)o*256 + lane*4);
  float4 hv = ld4(h2 + (size_t)b*256 + lane*4);
  float acc = hv.x*wv.x + hv.y*wv.y + hv.z*wv.z + hv.w*wv.w;
#pragma unroll
  for (int s = 1; s < 64; s <<= 1) acc += __shfl_xor(acc, s);
  if (lane == 0) out[(size_t)b*40 + o] = acc + bl3[o];
}

extern "C" void kernel_launch(void* const* d_in, const int* in_sizes, int n_in,
                              void* d_out, int out_size, void* d_ws, size_t ws_size,
                              hipStream_t stream) {
  (void)in_sizes; (void)n_in; (void)out_size; (void)ws_size;
  const float* x   = (const float*)d_in[0];
  const float* w1  = (const float*)d_in[1];
  const float* bn1 = (const float*)d_in[2];
  const float* w2  = (const float*)d_in[3];
  const float* bn2 = (const float*)d_in[4];
  const float* w3  = (const float*)d_in[5];
  const float* bn3 = (const float*)d_in[6];
  const float* w4  = (const float*)d_in[7];
  const float* bn4 = (const float*)d_in[8];
  const float* w5  = (const float*)d_in[9];
  const float* bn5 = (const float*)d_in[10];
  const float* wl1 = (const float*)d_in[11];
  const float* bn6 = (const float*)d_in[12];
  const float* wl2 = (const float*)d_in[13];
  const float* bn7 = (const float*)d_in[14];
  const float* wl3 = (const float*)d_in[15];
  const float* bl3 = (const float*)d_in[16];
  float* out = (float*)d_out;

  // workspace layout byte-identical to the verified round-3 kernel (no growth)
  float* ws    = (float*)d_ws;
  float* xt    = ws;                          // 65536
  float* sqb   = xt + 65536;                  // 16384
  int*   idxb  = (int*)(sqb + 16384);         // 327680 ints
  float* pd    = (float*)(idxb + 327680);     // 16777216 (Z aliases, used after topk)
  unsigned short* hlo = (unsigned short*)(pd + 16777216); // 8388608 ushorts (old h slot, same bytes)
  float* wlT1  = (float*)(hlo + 8388608);     // 256
  float* dT1   = wlT1 + 256;                  // 256
  float* bias1 = dT1 + 256;                   // 64
  float* bias2 = bias1 + 64;                  // 64
  float* bias3 = bias2 + 64;                  // 128
  float* bias4 = bias3 + 128;                 // 256
  float* b5    = bias4 + 256;                 // 1024
  float* pmax  = b5 + 1024;                   // 131072
  float* psum  = pmax + 131072;               // 131072
  float* pool  = psum + 131072;               // 32768 (unused; layout kept)
  float* h1b   = pool + 32768;                // 8192
  float* h2b   = h1b + 8192;                  // 4096
  unsigned short* hb   = (unsigned short*)(h2b + 4096);    // 16384*512 bf16
  unsigned short* wlB2 = hb + (size_t)16384*512;            // 4096 (dB2 contiguous after)
  unsigned short* dB2  = wlB2 + 4096;
  unsigned short* wlB3 = dB2 + 4096;                        // 8192 (dB3 contiguous)
  unsigned short* dB3  = wlB3 + 8192;
  unsigned short* wlB4 = dB3 + 8192;                        // 32768 (dB4 contiguous)
  unsigned short* dB4  = wlB4 + 32768;
  unsigned short* w5b  = dB4 + 32768;                       // 524288
  float* Z = pd;

  k_transpose<<<64, 256, 0, stream>>>(x, xt, hlo, sqb);
  k_prep_all<<<2225, 256, 0, stream>>>(w1, bn1, w2, bn2, w3, bn3, w4, bn4, w5, bn5,
                                       wlT1, dT1, bias1, wlB2, dB2, bias2,
                                       wlB3, dB3, bias3, wlB4, dB4, bias4, w5b, b5);

  // ---- L1 (Cin=3 -> Cout=64) ----
  k_pdm1<<<1024, 256, 0, stream>>>(hlo, sqb, pd);
  k_topk<<<2048, 256, 0, stream>>>(pd, idxb);
  k_uv1<<<2048, 256, 0, stream>>>(xt, wlT1, dT1, Z);
  k_gmax<64,16,true><<<1024, 256, 0, stream>>>(Z, bias1, idxb, hb, hlo, sqb);

  // ---- L2 (64 -> 64) ----
  k_pdm<64><<<1024, 256, 0, stream>>>(hb, hlo, sqb, pd);
  k_topk<<<2048, 256, 0, stream>>>(pd, idxb);
  k_uv<64><<<dim3(128,1), 256, 0, stream>>>(hb, wlB2, Z, 128);
  k_gmax<64,16,true><<<1024, 256, 0, stream>>>(Z, bias2, idxb, hb + 64, hlo + 64, sqb);

  // ---- L3 (64 -> 128) ----
  k_pdm<64><<<1024, 256, 0, stream>>>(hb + 64, hlo + 64, sqb, pd);
  k_topk<<<2048, 256, 0, stream>>>(pd, idxb);
  k_uv<64><<<dim3(128,2), 256, 0, stream>>>(hb + 64, wlB3, Z, 256);
  k_gmax<128,8,true><<<2048, 256, 0, stream>>>(Z, bias3, idxb, hb + 128, hlo + 128, sqb);

  // ---- L4 (128 -> 256; bf16 out only) ----
  k_pdm<128><<<1024, 256, 0, stream>>>(hb + 128, hlo + 128, sqb, pd);
  k_topk<<<2048, 256, 0, stream>>>(pd, idxb);
  k_uv<128><<<dim3(128,4), 256, 0, stream>>>(hb + 128, wlB4, Z, 512);
  k_gmax<256,4,false><<<4096, 256, 0, stream>>>(Z, bias4, idxb, hb + 256, nullptr, nullptr);

  // ---- conv5 + FC head (pool fused into fc1) ----
  k_conv5m<<<dim3(128,8), 256, 0, stream>>>(hb, w5b, b5, pmax, psum);
  k_fc1<<<dim3(32,16), 256, 0, stream>>>(pmax, psum, wl1, bn6, h1b);
  k_fc2<<<dim3(16,16), 256, 0, stream>>>(h1b, wl2, bn7, h2b);
  k_fc3<<<dim3(40,16), 64, 0, stream>>>(h2b, wl3, bl3, out);
}

// Round 11
// 402.391 us; speedup vs baseline: 1.2385x; 1.0489x over previous
//
#include <hip/hip_runtime.h>

#define BB 16
#define NN 1024
#define KNN 20
#define BNEPS 1e-5f

typedef __attribute__((ext_vector_type(8))) short short8;
typedef __attribute__((ext_vector_type(4))) float f32x4;

__device__ __forceinline__ float4 ld4(const float* p){ return *(const float4*)p; }
__device__ __forceinline__ void fma4(float4& a, float s, float4 w){
  a.x = fmaf(s, w.x, a.x); a.y = fmaf(s, w.y, a.y);
  a.z = fmaf(s, w.z, a.z); a.w = fmaf(s, w.w, a.w);
}
__device__ __forceinline__ void max4(float4& a, float4 v){
  a.x = fmaxf(a.x, v.x); a.y = fmaxf(a.y, v.y);
  a.z = fmaxf(a.z, v.z); a.w = fmaxf(a.w, v.w);
}
__device__ __forceinline__ unsigned short f2bf(float f){
  unsigned int u = __float_as_uint(f);
  u = (u + 0x7FFF + ((u >> 16) & 1)) >> 16;   // RNE, finite inputs
  return (unsigned short)u;
}
__device__ __forceinline__ float bf2f(unsigned short u){
  return __uint_as_float(((unsigned int)u) << 16);
}
__device__ __forceinline__ f32x4 mfma16(short8 a, short8 b, f32x4 c){
  return __builtin_amdgcn_mfma_f32_16x16x32_bf16(a, b, c, 0, 0, 0);
}

// build exact (value desc, index asc) top-3 of a lane's 16 row elements, excluding km bits
__device__ __forceinline__ void top3_build(const float* rp, int kmr,
                                           float& a0, float& a1, float& a2,
                                           int& i0, int& i1, int& i2){
  a0 = -1e30f; a1 = -1e30f; a2 = -1e30f; i0 = 0; i1 = 0; i2 = 0;
#pragma unroll
  for (int r = 0; r < 4; r++){
    float4 t = ld4(rp + r*4);
    float tv[4] = {t.x, t.y, t.z, t.w};
#pragma unroll
    for (int q = 0; q < 4; q++){
      int e = r*4 + q;
      float v = ((kmr >> e) & 1) ? -1e30f : tv[q];
      bool b0 = v > a0, b1 = v > a1, b2 = v > a2;
      a2 = b1 ? a1 : (b2 ? v : a2); i2 = b1 ? i1 : (b2 ? e : i2);
      a1 = b0 ? a0 : (b1 ? v : a1); i1 = b0 ? i0 : (b1 ? e : i1);
      a0 = b0 ? v  : a0;            i0 = b0 ? e : i0;
    }
  }
}

// ------------ shared device body: top-k v5 (k=20), 2 rows/wave, XCD-pinned ------------
__device__ __forceinline__ void topk_body(int bid, int tidx,
                                          const float* __restrict__ pd, int* __restrict__ idxOut){
  int w = tidx >> 6, lane = tidx & 63;
  const int xcd = bid & 7, j = bid >> 3;            // j 0..255
  const int b = xcd + ((j >> 7) << 3);
  const int local = j & 127;
  int bn0 = (b*128 + local)*8 + w*2;
  const float* row0 = pd + (size_t)bn0*NN + lane*16;
  const float* row1 = row0 + NN;

  float c0v[2], c1v[2], c2v[2];
  int   c0i[2], c1i[2], c2i[2];
  int   km[2] = {0, 0};
  top3_build(row0, 0, c0v[0], c1v[0], c2v[0], c0i[0], c1i[0], c2i[0]);
  top3_build(row1, 0, c0v[1], c1v[1], c2v[1], c0i[1], c1i[1], c2i[1]);

  int* out0 = idxOut + (size_t)bn0*KNN;
  int* out1 = out0 + KNN;
  for (int it = 0; it < KNN; it++){
    float g0 = c0v[0], g1 = c0v[1];
#pragma unroll
    for (int s = 1; s < 64; s <<= 1){
      g0 = fmaxf(g0, __shfl_xor(g0, s));
      g1 = fmaxf(g1, __shfl_xor(g1, s));
    }
    int o0 = __ffsll(__ballot(c0v[0] == g0)) - 1;
    int o1 = __ffsll(__ballot(c0v[1] == g1)) - 1;
    bool u0 = (lane == o0), u1 = (lane == o1);
    if (u0) out0[it] = lane*16 + c0i[0];
    if (u1) out1[it] = lane*16 + c0i[1];
    km[0] |= u0 ? (1 << c0i[0]) : 0;
    km[1] |= u1 ? (1 << c0i[1]) : 0;
    c0v[0] = u0 ? c1v[0] : c0v[0];  c0i[0] = u0 ? c1i[0] : c0i[0];
    c1v[0] = u0 ? c2v[0] : c1v[0];  c1i[0] = u0 ? c2i[0] : c1i[0];
    c2v[0] = u0 ? -1e30f : c2v[0];
    c0v[1] = u1 ? c1v[1] : c0v[1];  c0i[1] = u1 ? c1i[1] : c0i[1];
    c1v[1] = u1 ? c2v[1] : c1v[1];  c1i[1] = u1 ? c2i[1] : c1i[1];
    c2v[1] = u1 ? -1e30f : c2v[1];
    if (it < KNN-1){
      bool rp0 = (c0v[0] == -1e30f) && (km[0] != 0xFFFF);
      bool rp1 = (c0v[1] == -1e30f) && (km[1] != 0xFFFF);
      if (__ballot(rp0 || rp1)){
        if (rp0) top3_build(row0, km[0], c0v[0], c1v[0], c2v[0], c0i[0], c1i[0], c2i[0]);
        if (rp1) top3_build(row1, km[1], c0v[1], c1v[1], c2v[1], c0i[1], c1i[1], c2i[1]);
      }
    }
  }
}

// ---- merged init: transpose (blocks 0..63) + weight prep (blocks 64..) ----
__device__ __forceinline__ void prep_w_dev(int i, const float* w, const float* bnp,
                                           float* wlT, float* dT, float* bias, int Cin, int Cpad, int Cout){
  if (i >= Cpad*Cout) return;
  int c = i / Cout, o = i - c*Cout;
  float s = bnp[o] * rsqrtf(bnp[3*Cout+o] + BNEPS);
  float wl = (c < Cin) ? w[(size_t)o*2*Cin + c] : 0.f;
  float wr = (c < Cin) ? w[(size_t)o*2*Cin + Cin + c] : 0.f;
  wlT[i] = wl * s;
  dT[i]  = (wr - wl) * s;
  if (c == 0) bias[o] = bnp[Cout+o] - bnp[2*Cout+o]*s;
}
__device__ __forceinline__ void prep_wbf_dev(int i, const float* w, const float* bnp,
                                             unsigned short* wlB, unsigned short* dB, float* bias,
                                             int Cin, int Cout){
  if (i >= Cin*Cout) return;
  int o = i / Cin, c = i - o*Cin;
  float s = bnp[o] * rsqrtf(bnp[3*Cout+o] + BNEPS);
  float wl = w[(size_t)o*2*Cin + c] * s;
  float wr = w[(size_t)o*2*Cin + Cin + c] * s;
  wlB[i] = f2bf(wl);
  dB[i]  = f2bf(wr - wl);
  if (c == 0) bias[o] = bnp[Cout+o] - bnp[2*Cout+o]*s;
}

__global__ __launch_bounds__(256) void k_init(const float* __restrict__ x, float* __restrict__ xt,
                                              unsigned short* __restrict__ hlo, float* __restrict__ sq,
                                              const float* __restrict__ w1, const float* __restrict__ bn1,
                                              const float* __restrict__ w2, const float* __restrict__ bn2,
                                              const float* __restrict__ w3, const float* __restrict__ bn3,
                                              const float* __restrict__ w4, const float* __restrict__ bn4,
                                              const float* __restrict__ w5, const float* __restrict__ bn5,
                                              float* __restrict__ wlT1, float* __restrict__ dT1, float* __restrict__ bias1,
                                              unsigned short* __restrict__ wlB2, unsigned short* __restrict__ dB2, float* __restrict__ bias2,
                                              unsigned short* __restrict__ wlB3, unsigned short* __restrict__ dB3, float* __restrict__ bias3,
                                              unsigned short* __restrict__ wlB4, unsigned short* __restrict__ dB4, float* __restrict__ bias4,
                                              unsigned short* __restrict__ w5b, float* __restrict__ b5){
  const int t = threadIdx.x;
  if (blockIdx.x < 64){
    int i = blockIdx.x*256 + t;
    int b = i >> 10, n = i & 1023;
    const float* xb = x + (size_t)b*3*NN;
    float4 v;
    v.x = xb[0*NN+n]; v.y = xb[1*NN+n]; v.z = xb[2*NN+n]; v.w = 0.f;
    ((float4*)xt)[i] = v;
    unsigned short hx = f2bf(v.x), hy = f2bf(v.y), hz = f2bf(v.z);
    float rx = v.x - bf2f(hx), ry = v.y - bf2f(hy), rz = v.z - bf2f(hz);
    unsigned short lx = f2bf(rx), ly = f2bf(ry), lz = f2bf(rz);
    float ex = bf2f(hx)+bf2f(lx), ey = bf2f(hy)+bf2f(ly), ez = bf2f(hz)+bf2f(lz);
    sq[i] = ex*ex + ey*ey + ez*ez;          // consistent with Gram inputs
    ushort4 h4 = {hx, hy, hz, 0};
    ushort4 l4 = {lx, ly, lz, 0};
    ushort4 z4 = {0, 0, 0, 0};
    unsigned short* pa = hlo + (size_t)i*512 + 256;
    unsigned short* pb = hlo + (size_t)i*512 + 288;
    *(ushort4*)(pa+0) = h4; *(ushort4*)(pa+4) = l4; *(ushort4*)(pa+8) = h4;
    *(ushort4*)(pb+0) = h4; *(ushort4*)(pb+4) = h4; *(ushort4*)(pb+8) = l4;
#pragma unroll
    for (int s = 12; s < 32; s += 4){ *(ushort4*)(pa+s) = z4; *(ushort4*)(pb+s) = z4; }
    return;
  }
  int bid = blockIdx.x - 64;
  if (bid < 1){
    prep_w_dev(t, w1, bn1, wlT1, dT1, bias1, 3, 4, 64);
  } else if (bid < 17){
    prep_wbf_dev((bid-1)*256 + t, w2, bn2, wlB2, dB2, bias2, 64, 64);
  } else if (bid < 49){
    prep_wbf_dev((bid-17)*256 + t, w3, bn3, wlB3, dB3, bias3, 64, 128);
  } else if (bid < 177){
    prep_wbf_dev((bid-49)*256 + t, w4, bn4, wlB4, dB4, bias4, 128, 256);
  } else {
    int i = (bid-177)*256 + t;
    int o = i >> 9, c = i & 511;
    float s = bn5[o] * rsqrtf(bn5[3*1024+o] + BNEPS);
    w5b[i] = f2bf(w5[(size_t)o*512 + c] * s);
    if (c == 0) b5[o] = bn5[1024+o] - bn5[2*1024+o]*s;
  }
}

// -------- pd via split-bf16 MFMA Gram (fp32-equivalent: hi*hi + lo*hi + hi*lo) --------
// 1D grid 1024, XCD swizzle: bid&7 = XCD, batches {c, c+8} pinned per XCD.
// Epilogue staged through LDS: 256B-contiguous float4 row segments (full 128B lines).
template<int CC>
__global__ __launch_bounds__(256) void k_pdm(const unsigned short* __restrict__ hbi,
                                             const unsigned short* __restrict__ hlo,
                                             const float* __restrict__ sq,
                                             float* __restrict__ pd){
  __shared__ char sm[20480];
  char* As = sm; char* Bs = sm + 10240;
  const int tid = threadIdx.x, lane = tid & 63, w = tid >> 6;
  const int l15 = lane & 15, quad = lane >> 4;
  const int bid = blockIdx.x;
  const int xcd = bid & 7, j = bid >> 3;
  const int b = xcd + ((j >> 6) << 3);
  const int rt = (j >> 3) & 7, ct = j & 7;
  const size_t ar0 = (size_t)b*NN + rt*128;             // A global rows
  const size_t br0 = (size_t)b*NN + ct*128;             // B global rows (pd col base)
  const int colb = ct*128;

  f32x4 acc[2][8];
  f32x4 zero = {0.f,0.f,0.f,0.f};
#pragma unroll
  for (int i = 0; i < 2; i++)
#pragma unroll
    for (int j2 = 0; j2 < 8; j2++) acc[i][j2] = zero;

  for (int k0 = 0; k0 < 3*CC; k0 += 32){
    int seg = k0 / CC, off = k0 - seg*CC;
    const unsigned short* Ap = (seg == 1) ? hlo : hbi;  // hi, lo, hi
    const unsigned short* Bp = (seg == 2) ? hlo : hbi;  // hi, hi, lo
#pragma unroll
    for (int i = 0; i < 2; i++){
      int e = tid + i*256;
      int r = e >> 2, sg = e & 3;
      *(float4*)(As + r*80 + sg*16) = *(const float4*)(Ap + (ar0+r)*512 + off + sg*8);
      *(float4*)(Bs + r*80 + sg*16) = *(const float4*)(Bp + (br0+r)*512 + off + sg*8);
    }
    __syncthreads();
    short8 af0 = *(short8*)(As + (w*32 + l15)*80 + quad*16);
    short8 af1 = *(short8*)(As + (w*32 + 16 + l15)*80 + quad*16);
#pragma unroll
    for (int ns = 0; ns < 8; ns++){
      short8 bf = *(short8*)(Bs + (ns*16 + l15)*80 + quad*16);
      acc[0][ns] = mfma16(af0, bf, acc[0][ns]);
      acc[1][ns] = mfma16(af1, bf, acc[1][ns]);
    }
    __syncthreads();
  }

  // epilogue: 4 passes (ms, nh); stage 64 rows x 64 cols, store 256B/row full lines
  float* L = (float*)sm;
#pragma unroll
  for (int p = 0; p < 4; p++){
    const int ms = p >> 1, nh = p & 1;
    __syncthreads();
#pragma unroll
    for (int ns = 0; ns < 4; ns++){
      f32x4 a = acc[ms][nh*4 + ns];
      float sqv = sq[br0 + (nh*4+ns)*16 + l15];
#pragma unroll
      for (int r = 0; r < 4; r++)
        L[(w*16 + quad*4 + r)*68 + ns*16 + l15] = 2.f*a[r] - sqv;
    }
    __syncthreads();
#pragma unroll
    for (int k = 0; k < 4; k++){
      int e = tid + k*256;
      int lr = e >> 4, c4 = (e & 15)*4;
      int grow = (int)ar0 + (lr >> 4)*32 + ms*16 + (lr & 15);
      *(float4*)(pd + (size_t)grow*NN + colb + nh*64 + c4) = *(float4*)(L + lr*68 + c4);
    }
  }
}

// -------- L1 pd: packed K=32 operands embedded in hlo (row*512+256 / +288), one MFMA step ----
__global__ __launch_bounds__(256) void k_pdm1(const unsigned short* __restrict__ hlo,
                                              const float* __restrict__ sq,
                                              float* __restrict__ pd){
  __shared__ char sm[20480];
  char* As = sm; char* Bs = sm + 10240;
  const int tid = threadIdx.x, lane = tid & 63, w = tid >> 6;
  const int l15 = lane & 15, quad = lane >> 4;
  const int bid = blockIdx.x;
  const int xcd = bid & 7, j = bid >> 3;
  const int b = xcd + ((j >> 6) << 3);
  const int rt = (j >> 3) & 7, ct = j & 7;
  const size_t ar0 = (size_t)b*NN + rt*128;
  const size_t br0 = (size_t)b*NN + ct*128;
  const int colb = ct*128;

#pragma unroll
  for (int i = 0; i < 2; i++){
    int e = tid + i*256;
    int r = e >> 2, sg = e & 3;
    *(float4*)(As + r*80 + sg*16) = *(const float4*)(hlo + (ar0+r)*512 + 256 + sg*8);
    *(float4*)(Bs + r*80 + sg*16) = *(const float4*)(hlo + (br0+r)*512 + 288 + sg*8);
  }
  __syncthreads();

  f32x4 acc[2][8];
  f32x4 zero = {0.f,0.f,0.f,0.f};
#pragma unroll
  for (int i = 0; i < 2; i++)
#pragma unroll
    for (int j2 = 0; j2 < 8; j2++) acc[i][j2] = zero;

  short8 af0 = *(short8*)(As + (w*32 + l15)*80 + quad*16);
  short8 af1 = *(short8*)(As + (w*32 + 16 + l15)*80 + quad*16);
#pragma unroll
  for (int ns = 0; ns < 8; ns++){
    short8 bf = *(short8*)(Bs + (ns*16 + l15)*80 + quad*16);
    acc[0][ns] = mfma16(af0, bf, acc[0][ns]);
    acc[1][ns] = mfma16(af1, bf, acc[1][ns]);
  }

  float* L = (float*)sm;
#pragma unroll
  for (int p = 0; p < 4; p++){
    const int ms = p >> 1, nh = p & 1;
    __syncthreads();
#pragma unroll
    for (int ns = 0; ns < 4; ns++){
      f32x4 a = acc[ms][nh*4 + ns];
      float sqv = sq[br0 + (nh*4+ns)*16 + l15];
#pragma unroll
      for (int r = 0; r < 4; r++)
        L[(w*16 + quad*4 + r)*68 + ns*16 + l15] = 2.f*a[r] - sqv;
    }
    __syncthreads();
#pragma unroll
    for (int k = 0; k < 4; k++){
      int e = tid + k*256;
      int lr = e >> 4, c4 = (e & 15)*4;
      int grow = (int)ar0 + (lr >> 4)*32 + ms*16 + (lr & 15);
      *(float4*)(pd + (size_t)grow*NN + colb + nh*64 + c4) = *(float4*)(L + lr*68 + c4);
    }
  }
}

// ======== MERGED topk ∥ uv (independent: topk reads pd, uv writes separate Z) ========
// blocks 0..2047: topk; blocks 2048..: uv (bx = (bid-2048)&127, by = (bid-2048)>>7).
// 2048 ≡ 0 mod 8 so both halves keep their standalone XCD swizzle parity.
template<int K, int NY>
__global__ __launch_bounds__(256) void k_tkuv(const float* __restrict__ pd, int* __restrict__ idxOut,
                                              const unsigned short* __restrict__ hbi,
                                              const unsigned short* __restrict__ wB,
                                              float* __restrict__ Z, int ldz){
  __shared__ char sm[20480];
  if (blockIdx.x < 2048){
    topk_body(blockIdx.x, threadIdx.x, pd, idxOut);
    return;
  }
  char* As = sm; char* Bs = sm + 10240;
  const int tid = threadIdx.x, lane = tid & 63, w = tid >> 6;
  const int l15 = lane & 15, quad = lane >> 4;
  const int jj = blockIdx.x - 2048;
  const int bx = jj & 127;
  const int t = ((bx & 7) << 3) | ((bx >> 3) & 7) | (bx & 64);
  const int n0 = (jj >> 7)*128, r0 = t*128;

  f32x4 acc[2][8];
  f32x4 zero = {0.f,0.f,0.f,0.f};
#pragma unroll
  for (int i = 0; i < 2; i++)
#pragma unroll
    for (int j = 0; j < 8; j++) acc[i][j] = zero;

  for (int k0 = 0; k0 < K; k0 += 32){
#pragma unroll
    for (int i = 0; i < 2; i++){
      int e = tid + i*256;
      int r = e >> 2, sg = e & 3;
      *(float4*)(As + r*80 + sg*16) = *(const float4*)(hbi + ((size_t)(r0+r))*512 + k0 + sg*8);
      *(float4*)(Bs + r*80 + sg*16) = *(const float4*)(wB  + ((size_t)(n0+r))*K   + k0 + sg*8);
    }
    __syncthreads();
    short8 af0 = *(short8*)(As + (w*32 + l15)*80 + quad*16);
    short8 af1 = *(short8*)(As + (w*32 + 16 + l15)*80 + quad*16);
#pragma unroll
    for (int ns = 0; ns < 8; ns++){
      short8 bf = *(short8*)(Bs + (ns*16 + l15)*80 + quad*16);
      acc[0][ns] = mfma16(af0, bf, acc[0][ns]);
      acc[1][ns] = mfma16(af1, bf, acc[1][ns]);
    }
    __syncthreads();
  }

#pragma unroll
  for (int ms = 0; ms < 2; ms++){
#pragma unroll
    for (int ns = 0; ns < 8; ns++){
      f32x4 a = acc[ms][ns];
      int row = r0 + w*32 + ms*16 + quad*4;
      int col = n0 + ns*16 + l15;
#pragma unroll
      for (int r = 0; r < 4; r++)
        Z[(size_t)(row+r)*ldz + col] = a[r];
    }
  }
}

// -------- L1 merged: topk ∥ uv1 (blocks 0..2047 topk, 2048..4095 uv1) --------
__global__ __launch_bounds__(256) void k_tkuv1(const float* __restrict__ pd, int* __restrict__ idxOut,
                                               const float* __restrict__ xt,
                                               const float* __restrict__ wlT, const float* __restrict__ dT,
                                               float* __restrict__ Z){
  if (blockIdx.x < 2048){
    topk_body(blockIdx.x, threadIdx.x, pd, idxOut);
    return;
  }
  const int bid = blockIdx.x - 2048;   // 0..2047
  const int pb = ((bid >> 10) << 10) | ((bid & 7) << 7) | ((bid >> 3) & 127);
  int t = pb*256 + threadIdx.x;
  int n = t >> 5, q = t & 31;
  float4 xv = ld4(xt + (size_t)n*4);
  const float* wp = (q < 16) ? (wlT + q*4) : (dT + (q-16)*4);
  float4 a = make_float4(0.f,0.f,0.f,0.f);
  fma4(a, xv.x, ld4(wp + 0*64));
  fma4(a, xv.y, ld4(wp + 1*64));
  fma4(a, xv.z, ld4(wp + 2*64));
  fma4(a, xv.w, ld4(wp + 3*64));
  *(float4*)(Z + (size_t)n*128 + q*4) = a;
}

// ---------------- gather-max: emits bf16 hi (hb), bf16 lo (hlo), and fused sq ----------------
// block swizzle: blocks of batch b pinned to xcd b&7 (Z gather + hb/hlo writes L2-local).
template<int COUT, int P, bool WLO>
__global__ __launch_bounds__(256) void k_gmax(const float* __restrict__ Z,
                                              const float* __restrict__ bias,
                                              const int* __restrict__ knn_idx,
                                              unsigned short* __restrict__ hbo,
                                              unsigned short* __restrict__ hloo,
                                              float* __restrict__ sqo){
  constexpr int QPP = COUT/4;
  constexpr int BPB = 1024/P;                      // blocks per batch
  constexpr int SHF = (P == 16) ? 6 : (P == 8) ? 7 : 8;
  __shared__ int idxS[P*KNN];
  const int tid = threadIdx.x;
  const int bid = blockIdx.x;
  const int pb = ((bid >> (SHF+3)) << (SHF+3)) | ((bid & 7) << SHF) | ((bid >> 3) & (BPB-1));
  const int p0 = pb * P;
  for (int t = tid; t < P*KNN; t += 256) idxS[t] = knn_idx[(size_t)p0*KNN + t];
  __syncthreads();

  const int p = tid / QPP, q = tid - p*QPP;
  const int base = p0 & ~1023;
  const int ldz = 2*COUT;
  const float* Zq = Z + q*4;

  float4 m = make_float4(-1e30f,-1e30f,-1e30f,-1e30f);
#pragma unroll
  for (int j = 0; j < KNN; j++){
    int mr = idxS[p*KNN + j];
    max4(m, ld4(Zq + (size_t)(base + mr)*ldz));
  }
  float4 ctr = ld4(Z + (size_t)(p0+p)*ldz + COUT + q*4);
  float4 bs  = ld4(bias + q*4);
  float4 y;
  y.x = m.x + ctr.x + bs.x; y.x = fmaxf(y.x, 0.2f*y.x);
  y.y = m.y + ctr.y + bs.y; y.y = fmaxf(y.y, 0.2f*y.y);
  y.z = m.z + ctr.z + bs.z; y.z = fmaxf(y.z, 0.2f*y.z);
  y.w = m.w + ctr.w + bs.w; y.w = fmaxf(y.w, 0.2f*y.w);

  size_t pi = (size_t)(p0 + p);
  ushort4 hv; hv.x = f2bf(y.x); hv.y = f2bf(y.y); hv.z = f2bf(y.z); hv.w = f2bf(y.w);
  *(ushort4*)(hbo + pi*512 + q*4) = hv;
  if (WLO){
    ushort4 lv;
    lv.x = f2bf(y.x - bf2f(hv.x)); lv.y = f2bf(y.y - bf2f(hv.y));
    lv.z = f2bf(y.z - bf2f(hv.z)); lv.w = f2bf(y.w - bf2f(hv.w));
    *(ushort4*)(hloo + pi*512 + q*4) = lv;
    // fused sq (matches prior k_sqb arithmetic exactly)
    float ex = bf2f(hv.x)+bf2f(lv.x), ey = bf2f(hv.y)+bf2f(lv.y);
    float ez = bf2f(hv.z)+bf2f(lv.z), ew = bf2f(hv.w)+bf2f(lv.w);
    float s4 = ex*ex + ey*ey + ez*ez + ew*ew;
#pragma unroll
    for (int sh = 1; sh < QPP; sh <<= 1) s4 += __shfl_xor(s4, sh);
    if (q == 0) sqo[pi] = s4;
  }
}

// ---------------- conv5 (bf16 MFMA) + bias + lrelu + partial pool ----------------
__global__ __launch_bounds__(256) void k_conv5m(const unsigned short* __restrict__ hb,
                                                const unsigned short* __restrict__ w5b,
                                                const float* __restrict__ b5,
                                                float* __restrict__ pmax, float* __restrict__ psum){
  __shared__ char sm[20480 + 4096];
  char* As = sm; char* Bs = sm + 10240;
  float* red = (float*)(sm + 20480);
  const int tid = threadIdx.x, lane = tid & 63, w = tid >> 6;
  const int l15 = lane & 15, quad = lane >> 4;
  const int n0 = blockIdx.y*128, r0 = blockIdx.x*128;

  f32x4 acc[2][8];
  f32x4 zero = {0.f,0.f,0.f,0.f};
#pragma unroll
  for (int i = 0; i < 2; i++)
#pragma unroll
    for (int j = 0; j < 8; j++) acc[i][j] = zero;

  for (int k0 = 0; k0 < 512; k0 += 32){
#pragma unroll
    for (int i = 0; i < 2; i++){
      int e = tid + i*256;
      int r = e >> 2, sg = e & 3;
      *(float4*)(As + r*80 + sg*16) = *(const float4*)(hb  + ((size_t)(r0+r))*512 + k0 + sg*8);
      *(float4*)(Bs + r*80 + sg*16) = *(const float4*)(w5b + ((size_t)(n0+r))*512 + k0 + sg*8);
    }
    __syncthreads();
    short8 af0 = *(short8*)(As + (w*32 + l15)*80 + quad*16);
    short8 af1 = *(short8*)(As + (w*32 + 16 + l15)*80 + quad*16);
#pragma unroll
    for (int ns = 0; ns < 8; ns++){
      short8 bf = *(short8*)(Bs + (ns*16 + l15)*80 + quad*16);
      acc[0][ns] = mfma16(af0, bf, acc[0][ns]);
      acc[1][ns] = mfma16(af1, bf, acc[1][ns]);
    }
    __syncthreads();
  }

#pragma unroll
  for (int ns = 0; ns < 8; ns++){
    float bv = b5[n0 + ns*16 + l15];
    float mx = -1e30f, sum = 0.f;
#pragma unroll
    for (int ms = 0; ms < 2; ms++){
      float* a = (float*)&acc[ms][ns];
#pragma unroll
      for (int r = 0; r < 4; r++){
        float v = a[r] + bv; v = fmaxf(v, 0.2f*v);
        mx = fmaxf(mx, v); sum += v;
      }
    }
    for (int s = 16; s < 64; s <<= 1){
      mx = fmaxf(mx, __shfl_xor(mx, s));
      sum += __shfl_xor(sum, s);
    }
    if (quad == 0){ red[(w*8 + ns)*16 + l15] = mx; red[512 + (w*8 + ns)*16 + l15] = sum; }
  }
  __syncthreads();
  if (tid < 128){
    int ns = tid >> 4, ci = tid & 15;
    float mx = -1e30f, sum = 0.f;
#pragma unroll
    for (int w2 = 0; w2 < 4; w2++){
      mx = fmaxf(mx, red[(w2*8 + ns)*16 + ci]);
      sum += red[512 + (w2*8 + ns)*16 + ci];
    }
    pmax[(size_t)blockIdx.x*1024 + n0 + tid] = mx;
    psum[(size_t)blockIdx.x*1024 + n0 + tid] = sum;
  }
}

// ---------------- FC1: 2048->512, pool fused (max/mean over 8 chunks) ----------------
__global__ __launch_bounds__(256) void k_fc1(const float* __restrict__ pmax, const float* __restrict__ psum,
                                             const float* __restrict__ wl1, const float* __restrict__ bn6,
                                             float* __restrict__ h1){
  __shared__ float pS[2048];
  const int b = blockIdx.y, t = threadIdx.x;
  for (int f = t; f < 512; f += 256){
    float4 r;
    if (f < 256){
      r = ld4(pmax + (size_t)(b*8)*1024 + f*4);
#pragma unroll
      for (int ch = 1; ch < 8; ch++) max4(r, ld4(pmax + (size_t)(b*8+ch)*1024 + f*4));
    } else {
      int o = (f-256)*4;
      r = ld4(psum + (size_t)(b*8)*1024 + o);
#pragma unroll
      for (int ch = 1; ch < 8; ch++){
        float4 s = ld4(psum + (size_t)(b*8+ch)*1024 + o);
        r.x += s.x; r.y += s.y; r.z += s.z; r.w += s.w;
      }
      r.x *= (1.f/1024.f); r.y *= (1.f/1024.f); r.z *= (1.f/1024.f); r.w *= (1.f/1024.f);
    }
    ((float4*)pS)[f] = r;
  }
  __syncthreads();
  const int ol = t >> 4, ch = t & 15;
  const int o = blockIdx.x*16 + ol;
  const float* wr = wl1 + (size_t)o*2048;
  float acc = 0.f;
#pragma unroll
  for (int j = 0; j < 32; j++){
    int c = ch*4 + j*64;
    float4 wv = ld4(wr + c);
    acc += pS[c]*wv.x + pS[c+1]*wv.y + pS[c+2]*wv.z + pS[c+3]*wv.w;
  }
#pragma unroll
  for (int s = 1; s < 16; s <<= 1) acc += __shfl_xor(acc, s);
  if (ch == 0){
    float s = bn6[o] * rsqrtf(bn6[3*512+o] + BNEPS);
    float y = (acc - bn6[2*512+o])*s + bn6[512+o];
    h1[(size_t)b*512 + o] = fmaxf(y, 0.2f*y);
  }
}

// ---------------- FC2: 512->256 ----------------
__global__ __launch_bounds__(256) void k_fc2(const float* __restrict__ h1,
                                             const float* __restrict__ wl2, const float* __restrict__ bn7,
                                             float* __restrict__ h2){
  __shared__ float hS[512];
  const int b = blockIdx.y, t = threadIdx.x;
  if (t < 128) ((float4*)hS)[t] = ((const float4*)(h1 + (size_t)b*512))[t];
  __syncthreads();
  const int ol = t >> 4, ch = t & 15;
  const int o = blockIdx.x*16 + ol;
  const float* wr = wl2 + (size_t)o*512;
  float acc = 0.f;
#pragma unroll
  for (int j = 0; j < 8; j++){
    int c = ch*4 + j*64;
    float4 wv = ld4(wr + c);
    acc += hS[c]*wv.x + hS[c+1]*wv.y + hS[c+2]*wv.z + hS[c+3]*wv.w;
  }
#pragma unroll
  for (int s = 1; s < 16; s <<= 1) acc += __shfl_xor(acc, s);
  if (ch == 0){
    float s = bn7[o] * rsqrtf(bn7[3*256+o] + BNEPS);
    float y = (acc - bn7[2*256+o])*s + bn7[256+o];
    h2[(size_t)b*256 + o] = fmaxf(y, 0.2f*y);
  }
}

// ---------------- FC3: 256->40 ----------------
__global__ __launch_bounds__(64) void k_fc3(const float* __restrict__ h2,
                                            const float* __restrict__ wl3, const float* __restrict__ bl3,
                                            float* __restrict__ out){
  const int o = blockIdx.x, b = blockIdx.y, lane = threadIdx.x;
  float4 wv = ld4(wl3 + (size_t)o*256 + lane*4);
  float4 hv = ld4(h2 + (size_t)b*256 + lane*4);
  float acc = hv.x*wv.x + hv.y*wv.y + hv.z*wv.z + hv.w*wv.w;
#pragma unroll
  for (int s = 1; s < 64; s <<= 1) acc += __shfl_xor(acc, s);
  if (lane == 0) out[(size_t)b*40 + o] = acc + bl3[o];
}

extern "C" void kernel_launch(void* const* d_in, const int* in_sizes, int n_in,
                              void* d_out, int out_size, void* d_ws, size_t ws_size,
                              hipStream_t stream) {
  (void)in_sizes; (void)n_in; (void)out_size; (void)ws_size;
  const float* x   = (const float*)d_in[0];
  const float* w1  = (const float*)d_in[1];
  const float* bn1 = (const float*)d_in[2];
  const float* w2  = (const float*)d_in[3];
  const float* bn2 = (const float*)d_in[4];
  const float* w3  = (const float*)d_in[5];
  const float* bn3 = (const float*)d_in[6];
  const float* w4  = (const float*)d_in[7];
  const float* bn4 = (const float*)d_in[8];
  const float* w5  = (const float*)d_in[9];
  const float* bn5 = (const float*)d_in[10];
  const float* wl1 = (const float*)d_in[11];
  const float* bn6 = (const float*)d_in[12];
  const float* wl2 = (const float*)d_in[13];
  const float* bn7 = (const float*)d_in[14];
  const float* wl3 = (const float*)d_in[15];
  const float* bl3 = (const float*)d_in[16];
  float* out = (float*)d_out;

  // layout = verified R10 layout + Zbuf appended after w5b (ws_size ≈ 268MB per
  // harness fill WRITE_SIZE; layout ends ~138MB — safely inside).
  float* ws    = (float*)d_ws;
  float* xt    = ws;                          // 65536
  float* sqb   = xt + 65536;                  // 16384
  int*   idxb  = (int*)(sqb + 16384);         // 327680 ints
  float* pd    = (float*)(idxb + 327680);     // 16777216 (pd only — Z un-aliased)
  unsigned short* hlo = (unsigned short*)(pd + 16777216); // 8388608 ushorts
  float* wlT1  = (float*)(hlo + 8388608);     // 256
  float* dT1   = wlT1 + 256;                  // 256
  float* bias1 = dT1 + 256;                   // 64
  float* bias2 = bias1 + 64;                  // 64
  float* bias3 = bias2 + 64;                  // 128
  float* bias4 = bias3 + 128;                 // 256
  float* b5    = bias4 + 256;                 // 1024
  float* pmax  = b5 + 1024;                   // 131072
  float* psum  = pmax + 131072;               // 131072
  float* pool  = psum + 131072;               // 32768 (unused; layout kept)
  float* h1b   = pool + 32768;                // 8192
  float* h2b   = h1b + 8192;                  // 4096
  unsigned short* hb   = (unsigned short*)(h2b + 4096);    // 16384*512 bf16
  unsigned short* wlB2 = hb + (size_t)16384*512;            // 4096
  unsigned short* dB2  = wlB2 + 4096;
  unsigned short* wlB3 = dB2 + 4096;                        // 8192
  unsigned short* dB3  = wlB3 + 8192;
  unsigned short* wlB4 = dB3 + 8192;                        // 32768
  unsigned short* dB4  = wlB4 + 32768;
  unsigned short* w5b  = dB4 + 32768;                       // 524288
  float* Z = (float*)(w5b + 524288);                        // 16384*512 f32 (33.5MB, max ldz=512)

  k_init<<<2289, 256, 0, stream>>>(x, xt, hlo, sqb,
                                   w1, bn1, w2, bn2, w3, bn3, w4, bn4, w5, bn5,
                                   wlT1, dT1, bias1, wlB2, dB2, bias2,
                                   wlB3, dB3, bias3, wlB4, dB4, bias4, w5b, b5);

  // ---- L1 (Cin=3 -> Cout=64) ----
  k_pdm1<<<1024, 256, 0, stream>>>(hlo, sqb, pd);
  k_tkuv1<<<4096, 256, 0, stream>>>(pd, idxb, xt, wlT1, dT1, Z);
  k_gmax<64,16,true><<<1024, 256, 0, stream>>>(Z, bias1, idxb, hb, hlo, sqb);

  // ---- L2 (64 -> 64) ----
  k_pdm<64><<<1024, 256, 0, stream>>>(hb, hlo, sqb, pd);
  k_tkuv<64,1><<<2048+128, 256, 0, stream>>>(pd, idxb, hb, wlB2, Z, 128);
  k_gmax<64,16,true><<<1024, 256, 0, stream>>>(Z, bias2, idxb, hb + 64, hlo + 64, sqb);

  // ---- L3 (64 -> 128) ----
  k_pdm<64><<<1024, 256, 0, stream>>>(hb + 64, hlo + 64, sqb, pd);
  k_tkuv<64,2><<<2048+256, 256, 0, stream>>>(pd, idxb, hb + 64, wlB3, Z, 256);
  k_gmax<128,8,true><<<2048, 256, 0, stream>>>(Z, bias3, idxb, hb + 128, hlo + 128, sqb);

  // ---- L4 (128 -> 256; bf16 out only) ----
  k_pdm<128><<<1024, 256, 0, stream>>>(hb + 128, hlo + 128, sqb, pd);
  k_tkuv<128,4><<<2048+512, 256, 0, stream>>>(pd, idxb, hb + 128, wlB4, Z, 512);
  k_gmax<256,4,false><<<4096, 256, 0, stream>>>(Z, bias4, idxb, hb + 256, nullptr, nullptr);

  // ---- conv5 + FC head (pool fused into fc1) ----
  k_conv5m<<<dim3(128,8), 256, 0, stream>>>(hb, w5b, b5, pmax, psum);
  k_fc1<<<dim3(32,16), 256, 0, stream>>>(pmax, psum, wl1, bn6, h1b);
  k_fc2<<<dim3(16,16), 256, 0, stream>>>(h1b, wl2, bn7, h2b);
  k_fc3<<<dim3(40,16), 64, 0, stream>>>(h2b, wl3, bl3, out);
}